// Round 2
// baseline (577.540 us; speedup 1.0000x reference)
//
#include <hip/hip_runtime.h>
#include <stdint.h>

#define NN 8000            // nodes
#define UU 64              // units
#define EE 64000           // edges per support
#define BB 32              // batch
#define NB 256000          // NN*BB rows of the logical GEMM
#define KP 352             // padded K (5*64 state + 5*2 input + pad)
#define HXS 512000         // NN*UU (per-batch stride in hx)

typedef __attribute__((ext_vector_type(8))) __bf16 bf16x8;
typedef __attribute__((ext_vector_type(4))) float f32x4;
static_assert(sizeof(bf16x8) == 16, "bf16x8 must be 16B");

__device__ __forceinline__ unsigned short f2bf(float f){
  unsigned int u = __builtin_bit_cast(unsigned int, f);
  u += 0x7fffu + ((u >> 16) & 1u);
  return (unsigned short)(u >> 16);
}
__device__ __forceinline__ unsigned int pack2(float a, float b){
  return (unsigned int)f2bf(a) | ((unsigned int)f2bf(b) << 16);
}
__device__ __forceinline__ float bflo(unsigned int w){ return __builtin_bit_cast(float, w << 16); }
__device__ __forceinline__ float bfhi(unsigned int w){ return __builtin_bit_cast(float, w & 0xffff0000u); }
__device__ __forceinline__ float bfu(unsigned short v){ return __builtin_bit_cast(float, (unsigned int)v << 16); }

// ---------------- CSR build ----------------
__global__ void k_hist(const int* __restrict__ r0, const int* __restrict__ r1, int* __restrict__ cnt){
  int i = blockIdx.x * 256 + threadIdx.x;
  if (i < 2*EE){
    int s = (i >= EE);
    int r = s ? r1[i - EE] : r0[i];
    atomicAdd(&cnt[s*NN + r], 1);
  }
}

__global__ __launch_bounds__(1024) void k_scan(const int* __restrict__ cnt, int* __restrict__ row_ptr, int* __restrict__ rp_work){
  int sup = blockIdx.x;
  const int* c = cnt + sup*NN;
  __shared__ int part[1024];
  int t = threadIdx.x;
  int loc[8]; int s = 0;
  #pragma unroll
  for (int j=0;j<8;j++){ int idx=t*8+j; int v = (idx<NN)? c[idx]:0; loc[j]=s; s+=v; }
  part[t]=s; __syncthreads();
  for (int o=1;o<1024;o<<=1){
    int v = (t>=o)? part[t-o]:0;
    __syncthreads();
    part[t]+=v;
    __syncthreads();
  }
  int pre = (t>0)? part[t-1]:0;
  #pragma unroll
  for (int j=0;j<8;j++){ int idx=t*8+j; if(idx<NN){ int e=pre+loc[j]; row_ptr[sup*(NN+1)+idx]=e; rp_work[sup*NN+idx]=e; } }
  if (t==1023) row_ptr[sup*(NN+1)+NN] = part[1023];
}

__global__ void k_scatter(const int* __restrict__ r0, const int* __restrict__ c0, const float* __restrict__ v0,
                          const int* __restrict__ r1, const int* __restrict__ c1, const float* __restrict__ v1,
                          int* __restrict__ rp_work, int* __restrict__ col_s, float* __restrict__ val_s){
  int i = blockIdx.x * 256 + threadIdx.x;
  if (i < 2*EE){
    int s = (i >= EE);
    int e = s ? i - EE : i;
    int r  = s ? r1[e] : r0[e];
    int cc = s ? c1[e] : c0[e];
    float vv = s ? v1[e] : v0[e];
    int pos = atomicAdd(&rp_work[s*NN + r], 1);
    col_s[s*EE + pos] = cc;
    val_s[s*EE + pos] = vv;
  }
}

// ---------------- weight repack (Chebyshev absorbed), transposed [o][k], bf16 ----------------
__global__ void k_wpack(const float* __restrict__ W_ru, const float* __restrict__ W_c,
                        unsigned short* __restrict__ Wru_t, unsigned short* __restrict__ Wc_t){
  int i = blockIdx.x * 256 + threadIdx.x;   // 352*192 total
  int k = i / 192; int oo = i % 192;
  const float* W; int ld; unsigned short* dst; int o;
  if (oo < 128){ W = W_ru; ld = 128; dst = Wru_t; o = oo; }
  else         { W = W_c;  ld = 64;  dst = Wc_t;  o = oo - 128; }
  float v = 0.f;
  if (k < 330){
    int m, fb;
    if (k < 320){ m = k >> 6; fb = (2 + (k & 63)) * 5; }
    else        { int j = k - 320; m = j >> 1; fb = (j & 1) * 5; }
    if      (m==0) v = W[(fb+0)*ld+o] - W[(fb+2)*ld+o] - W[(fb+4)*ld+o];
    else if (m==1) v = W[(fb+1)*ld+o];
    else if (m==2) v = 2.f*W[(fb+2)*ld+o];
    else if (m==3) v = W[(fb+3)*ld+o];
    else           v = 2.f*W[(fb+4)*ld+o];
  }
  dst[o*KP + k] = f2bf(v);
}

// ---------------- build x0 (transpose + bf16) ----------------
__global__ void k_x0(const float* __restrict__ inputs, const float* __restrict__ hx,
                     unsigned int* __restrict__ xs0_dw, unsigned int* __restrict__ xsin0_dw){
  int n = blockIdx.x, t = threadIdx.x;
  int up = t & 31, bq = t >> 5;
  #pragma unroll
  for (int i=0;i<4;i++){
    int b = bq*4 + i;
    const float2 h = *(const float2*)(hx + (size_t)b*HXS + n*64 + up*2);
    xs0_dw[(n*32 + b)*32 + up] = pack2(h.x, h.y);
  }
  if (t < 32){
    int b = t;
    const float2 g = *(const float2*)(inputs + (size_t)b*(NN*2) + n*2);
    xsin0_dw[n*32 + b] = pack2(g.x, g.y);
  }
}

// ---------------- SpMM: dst[n] = sum_{e in row n} val_e * src[col_e] ----------------
template<bool WITH_IN>
__global__ void k_spmm(const int* __restrict__ row_ptr, const int* __restrict__ col_s, const float* __restrict__ val_s,
                       const uint4* __restrict__ srcS, uint4* __restrict__ dstS,
                       const uint4* __restrict__ srcI, uint4* __restrict__ dstI){
  int n = blockIdx.x, t = threadIdx.x;
  int beg = row_ptr[n], end = row_ptr[n+1];
  float a[8] = {0.f,0.f,0.f,0.f,0.f,0.f,0.f,0.f};
  float ai[8] = {0.f,0.f,0.f,0.f,0.f,0.f,0.f,0.f};
  for (int e = beg; e < end; ++e){
    int c = col_s[e];
    float v = val_s[e];
    uint4 q = srcS[(size_t)c*256 + t];
    a[0]+=v*bflo(q.x); a[1]+=v*bfhi(q.x); a[2]+=v*bflo(q.y); a[3]+=v*bfhi(q.y);
    a[4]+=v*bflo(q.z); a[5]+=v*bfhi(q.z); a[6]+=v*bflo(q.w); a[7]+=v*bfhi(q.w);
    if (WITH_IN && t < 8){
      uint4 qi = srcI[(size_t)c*8 + t];
      ai[0]+=v*bflo(qi.x); ai[1]+=v*bfhi(qi.x); ai[2]+=v*bflo(qi.y); ai[3]+=v*bfhi(qi.y);
      ai[4]+=v*bflo(qi.z); ai[5]+=v*bfhi(qi.z); ai[6]+=v*bflo(qi.w); ai[7]+=v*bfhi(qi.w);
    }
  }
  uint4 o;
  o.x = pack2(a[0],a[1]); o.y = pack2(a[2],a[3]); o.z = pack2(a[4],a[5]); o.w = pack2(a[6],a[7]);
  dstS[(size_t)n*256 + t] = o;
  if (WITH_IN && t < 8){
    uint4 oi;
    oi.x = pack2(ai[0],ai[1]); oi.y = pack2(ai[2],ai[3]); oi.z = pack2(ai[4],ai[5]); oi.w = pack2(ai[6],ai[7]);
    dstI[(size_t)n*8 + t] = oi;
  }
}

// ---------------- fused GEMM: no LDS, direct-global MFMA fragments ----------------
// A rows: wave-private, each 16B k-unit read exactly once -> pure stream.
// B (weights, <=90KB) is L2-hot across all blocks.
template<int NCOL, bool IS_RU>
__global__ __launch_bounds__(256) void k_gemm(const unsigned short* xsS,            // [5][NB][64] bf16
                                              const unsigned int* __restrict__ xsI, // [5][NB] dword(2 bf16)
                                              const unsigned short* __restrict__ Wt,// [NCOL][KP] bf16
                                              const float* __restrict__ bias,
                                              const float* __restrict__ hx,
                                              float* cout,                          // !IS_RU: d_out
                                              unsigned short* rhx_dst,              // IS_RU: xs_state[0]
                                              unsigned short* ubuf){                // u gate, bf16 [b][n][u] layout
  constexpr int CF = NCOL / 16;
  const int t = threadIdx.x;
  const int wv = t >> 6;
  const int l = t & 63;
  const int lr = l & 15;
  const int lg = l >> 4;
  const int R0 = blockIdx.x * 128;
  const int rowA0 = R0 + wv*32 + lr;

  f32x4 acc[2][CF];
  const f32x4 zero = {0.f, 0.f, 0.f, 0.f};
  #pragma unroll
  for (int rf=0; rf<2; rf++)
    #pragma unroll
    for (int cf=0; cf<CF; cf++) acc[rf][cf] = zero;

  #pragma unroll
  for (int m=0; m<5; m++){
    #pragma unroll
    for (int ks=0; ks<2; ks++){
      bf16x8 af[2];
      #pragma unroll
      for (int rf=0; rf<2; rf++){
        const uint4* p = (const uint4*)(xsS + ((size_t)m*NB + rowA0 + rf*16)*64 + ks*32 + lg*8);
        af[rf] = __builtin_bit_cast(bf16x8, *p);
      }
      #pragma unroll
      for (int cf=0; cf<CF; cf++){
        const uint4* p = (const uint4*)(Wt + (size_t)(cf*16 + lr)*KP + m*64 + ks*32 + lg*8);
        bf16x8 bv = __builtin_bit_cast(bf16x8, *p);
        acc[0][cf] = __builtin_amdgcn_mfma_f32_16x16x32_bf16(af[0], bv, acc[0][cf], 0, 0, 0);
        acc[1][cf] = __builtin_amdgcn_mfma_f32_16x16x32_bf16(af[1], bv, acc[1][cf], 0, 0, 0);
      }
    }
  }
  // remainder K-step: input features, k_local = m*2+d (10 real of 32)
  {
    bf16x8 af[2];
    #pragma unroll
    for (int rf=0; rf<2; rf++){
      int rg = rowA0 + rf*16;
      unsigned int q0=0u,q1=0u,q2=0u,q3=0u;
      if (lg == 0){
        q0 = xsI[rg]; q1 = xsI[NB + rg]; q2 = xsI[2*NB + rg]; q3 = xsI[3*NB + rg];
      } else if (lg == 1){
        q0 = xsI[4*NB + rg];
      }
      uint4 qq; qq.x=q0; qq.y=q1; qq.z=q2; qq.w=q3;
      af[rf] = __builtin_bit_cast(bf16x8, qq);
    }
    #pragma unroll
    for (int cf=0; cf<CF; cf++){
      const uint4* p = (const uint4*)(Wt + (size_t)(cf*16 + lr)*KP + 320 + lg*8);
      bf16x8 bv = __builtin_bit_cast(bf16x8, *p);
      acc[0][cf] = __builtin_amdgcn_mfma_f32_16x16x32_bf16(af[0], bv, acc[0][cf], 0, 0, 0);
      acc[1][cf] = __builtin_amdgcn_mfma_f32_16x16x32_bf16(af[1], bv, acc[1][cf], 0, 0, 0);
    }
  }
  // epilogue: C/D layout col=lane&15, row=(lane>>4)*4+reg
  #pragma unroll
  for (int rf=0; rf<2; rf++){
    #pragma unroll
    for (int reg=0; reg<4; reg++){
      int row = R0 + wv*32 + rf*16 + (lg << 2) + reg;
      int n = row >> 5, b = row & 31;
      size_t rowoff = (size_t)b*HXS + (size_t)n*UU;
      #pragma unroll
      for (int cf=0; cf<CF; cf++){
        int col = cf*16 + lr;
        float v = acc[rf][cf][reg] + bias[col];
        if constexpr (IS_RU){
          float sg = 1.f / (1.f + __expf(-v));
          if (cf < 4){ // r gate: write r*hx bf16 into xs_state[0] (in place, block-private rows)
            float h = hx[rowoff + col];
            rhx_dst[(size_t)row*64 + col] = f2bf(sg * h);
          } else {     // u gate, bf16
            ubuf[rowoff + (col - 64)] = f2bf(sg);
          }
        } else {
          float cc = tanhf(v);
          float uu = bfu(ubuf[rowoff + col]);
          float h  = hx[rowoff + col];
          cout[rowoff + col] = uu*h + (1.f - uu)*cc;
        }
      }
    }
  }
}

// ---------------- launcher ----------------
extern "C" void kernel_launch(void* const* d_in, const int* in_sizes, int n_in,
                              void* d_out, int out_size, void* d_ws, size_t ws_size,
                              hipStream_t stream){
  const float* inputs = (const float*)d_in[0];
  const float* hx     = (const float*)d_in[1];
  const int*   row0   = (const int*)d_in[2];
  const int*   col0   = (const int*)d_in[3];
  const float* val0   = (const float*)d_in[4];
  const int*   row1   = (const int*)d_in[5];
  const int*   col1   = (const int*)d_in[6];
  const float* val1   = (const float*)d_in[7];
  const float* W_ru   = (const float*)d_in[8];
  const float* b_ru   = (const float*)d_in[9];
  const float* W_c    = (const float*)d_in[10];
  const float* b_c    = (const float*)d_in[11];
  float* out = (float*)d_out;

  char* ws = (char*)d_ws;
  size_t off = 0;
  auto alloc = [&](size_t bytes) -> void* {
    void* p = ws + off;
    off += (bytes + 255) & ~(size_t)255;
    return p;
  };
  unsigned short* xsS   = (unsigned short*)alloc((size_t)5*NB*64*2); // 163.84 MB
  unsigned int*   xsI   = (unsigned int*)  alloc((size_t)5*NB*4);    //   5.12 MB
  unsigned short* u_buf = (unsigned short*)alloc((size_t)NB*64*2);   //  32.77 MB
  unsigned short* Wru_t = (unsigned short*)alloc(128*KP*2);
  unsigned short* Wc_t  = (unsigned short*)alloc(64*KP*2);
  int*   row_ptr = (int*)  alloc(2*(NN+1)*4);
  int*   col_s   = (int*)  alloc(2*EE*4);
  float* val_s   = (float*)alloc(2*EE*4);
  int*   cnt     = (int*)  alloc(2*NN*4);
  int*   rp_work = (int*)  alloc(2*NN*4);
  (void)ws_size; (void)in_sizes; (void)n_in; (void)out_size;

  hipMemsetAsync(cnt, 0, 2*NN*4, stream);
  k_hist<<<(2*EE + 255)/256, 256, 0, stream>>>(row0, row1, cnt);
  k_scan<<<2, 1024, 0, stream>>>(cnt, row_ptr, rp_work);
  k_scatter<<<(2*EE + 255)/256, 256, 0, stream>>>(row0, col0, val0, row1, col1, val1, rp_work, col_s, val_s);
  k_wpack<<<(KP*192)/256, 256, 0, stream>>>(W_ru, W_c, Wru_t, Wc_t);
  k_x0<<<NN, 256, 0, stream>>>(inputs, hx, (unsigned int*)xsS, xsI);

  auto spmm = [&](int sup, int srcm, int dstm, bool win){
    const int* rp = row_ptr + sup*(NN+1);
    const int* cs = col_s + sup*EE;
    const float* vs = val_s + sup*EE;
    const uint4* sS = (const uint4*)(xsS + (size_t)srcm*NB*64);
    uint4* dS = (uint4*)(xsS + (size_t)dstm*NB*64);
    const uint4* sI = (const uint4*)(xsI + (size_t)srcm*NB);
    uint4* dI = (uint4*)(xsI + (size_t)dstm*NB);
    if (win) k_spmm<true ><<<NN, 256, 0, stream>>>(rp, cs, vs, sS, dS, sI, dI);
    else     k_spmm<false><<<NN, 256, 0, stream>>>(rp, cs, vs, sS, dS, nullptr, nullptr);
  };

  // gconv 1 (r,u gates): diffuse state+input features
  spmm(0, 0, 1, true);
  spmm(0, 1, 2, true);
  spmm(1, 0, 3, true);
  spmm(1, 3, 4, true);
  k_gemm<128, true><<<NB/128, 256, 0, stream>>>(xsS, xsI, Wru_t, b_ru, hx, nullptr, xsS, u_buf);

  // gconv 2 (candidate): input-part diffusion reused from gconv1; state part = r*hx (in xs_state[0])
  spmm(0, 0, 1, false);
  spmm(0, 1, 2, false);
  spmm(1, 0, 3, false);
  spmm(1, 3, 4, false);
  k_gemm<64, false><<<NB/128, 256, 0, stream>>>(xsS, xsI, Wc_t, b_c, hx, out, xsS, u_buf);
}

// Round 3
// 517.196 us; speedup vs baseline: 1.1167x; 1.1167x over previous
//
#include <hip/hip_runtime.h>
#include <stdint.h>

#define NN 8000            // nodes
#define UU 64              // units
#define EE 64000           // edges per support
#define BB 32              // batch
#define NB 256000          // NN*BB rows of the logical GEMM
#define KP 352             // padded K (5*64 state + 5*2 input + pad)
#define HXS 512000         // NN*UU (per-batch stride in hx)
#define SLAB 2048000       // NN*4*64 shorts per (matrix,slice) slab
#define SLAB4 256000       // NN*32 uint4 per slab

typedef __attribute__((ext_vector_type(8))) __bf16 bf16x8;
typedef __attribute__((ext_vector_type(4))) float f32x4;
static_assert(sizeof(bf16x8) == 16, "bf16x8 must be 16B");

__device__ __forceinline__ unsigned short f2bf(float f){
  unsigned int u = __builtin_bit_cast(unsigned int, f);
  u += 0x7fffu + ((u >> 16) & 1u);
  return (unsigned short)(u >> 16);
}
__device__ __forceinline__ unsigned int pack2(float a, float b){
  return (unsigned int)f2bf(a) | ((unsigned int)f2bf(b) << 16);
}
__device__ __forceinline__ float bflo(unsigned int w){ return __builtin_bit_cast(float, w << 16); }
__device__ __forceinline__ float bfhi(unsigned int w){ return __builtin_bit_cast(float, w & 0xffff0000u); }
__device__ __forceinline__ float bfu(unsigned short v){ return __builtin_bit_cast(float, (unsigned int)v << 16); }

// async global->LDS, 16B per lane. lds base must be wave-uniform; lane offset implicit.
__device__ __forceinline__ void stage16(const unsigned short* g, unsigned short* ldsbase, int lane){
#if __has_builtin(__builtin_amdgcn_global_load_lds)
  __builtin_amdgcn_global_load_lds((const __attribute__((address_space(1))) void*)g,
                                   (__attribute__((address_space(3))) void*)ldsbase, 16, 0, 0);
#else
  *(uint4*)(ldsbase + lane*8) = *(const uint4*)g;
#endif
}

// ---------------- CSR build ----------------
__global__ void k_hist(const int* __restrict__ r0, const int* __restrict__ r1, int* __restrict__ cnt){
  int i = blockIdx.x * 256 + threadIdx.x;
  if (i < 2*EE){
    int s = (i >= EE);
    int r = s ? r1[i - EE] : r0[i];
    atomicAdd(&cnt[s*NN + r], 1);
  }
}

__global__ __launch_bounds__(1024) void k_scan(const int* __restrict__ cnt, int* __restrict__ row_ptr, int* __restrict__ rp_work){
  int sup = blockIdx.x;
  const int* c = cnt + sup*NN;
  __shared__ int part[1024];
  int t = threadIdx.x;
  int loc[8]; int s = 0;
  #pragma unroll
  for (int j=0;j<8;j++){ int idx=t*8+j; int v = (idx<NN)? c[idx]:0; loc[j]=s; s+=v; }
  part[t]=s; __syncthreads();
  for (int o=1;o<1024;o<<=1){
    int v = (t>=o)? part[t-o]:0;
    __syncthreads();
    part[t]+=v;
    __syncthreads();
  }
  int pre = (t>0)? part[t-1]:0;
  #pragma unroll
  for (int j=0;j<8;j++){ int idx=t*8+j; if(idx<NN){ int e=pre+loc[j]; row_ptr[sup*(NN+1)+idx]=e; rp_work[sup*NN+idx]=e; } }
  if (t==1023) row_ptr[sup*(NN+1)+NN] = part[1023];
}

__global__ void k_scatter(const int* __restrict__ r0, const int* __restrict__ c0, const float* __restrict__ v0,
                          const int* __restrict__ r1, const int* __restrict__ c1, const float* __restrict__ v1,
                          int* __restrict__ rp_work, int* __restrict__ col_s, float* __restrict__ val_s){
  int i = blockIdx.x * 256 + threadIdx.x;
  if (i < 2*EE){
    int s = (i >= EE);
    int e = s ? i - EE : i;
    int r  = s ? r1[e] : r0[e];
    int cc = s ? c1[e] : c0[e];
    float vv = s ? v1[e] : v0[e];
    int pos = atomicAdd(&rp_work[s*NN + r], 1);
    col_s[s*EE + pos] = cc;
    val_s[s*EE + pos] = vv;
  }
}

// ---------------- weight repack (Chebyshev absorbed), transposed [o][k], bf16 ----------------
__global__ void k_wpack(const float* __restrict__ W_ru, const float* __restrict__ W_c,
                        unsigned short* __restrict__ Wru_t, unsigned short* __restrict__ Wc_t){
  int i = blockIdx.x * 256 + threadIdx.x;   // 352*192 total
  int k = i / 192; int oo = i % 192;
  const float* W; int ld; unsigned short* dst; int o;
  if (oo < 128){ W = W_ru; ld = 128; dst = Wru_t; o = oo; }
  else         { W = W_c;  ld = 64;  dst = Wc_t;  o = oo - 128; }
  float v = 0.f;
  if (k < 330){
    int m, fb;
    if (k < 320){ m = k >> 6; fb = (2 + (k & 63)) * 5; }
    else        { int j = k - 320; m = j >> 1; fb = (j & 1) * 5; }
    if      (m==0) v = W[(fb+0)*ld+o] - W[(fb+2)*ld+o] - W[(fb+4)*ld+o];
    else if (m==1) v = W[(fb+1)*ld+o];
    else if (m==2) v = 2.f*W[(fb+2)*ld+o];
    else if (m==3) v = W[(fb+3)*ld+o];
    else           v = 2.f*W[(fb+4)*ld+o];
  }
  dst[o*KP + k] = f2bf(v);
}

// ---------------- build x0 (transpose + bf16, XCD-sliced slabs) ----------------
// xsS slab(m,s): [NN][4 bin][64 u] bf16 ; xsI slab(m,s): [NN] x uint4 (4 bins x dword)
__global__ void k_x0(const float* __restrict__ inputs, const float* __restrict__ hx,
                     unsigned int* __restrict__ xs0_dw, uint4* __restrict__ xsI4){
  int n = blockIdx.x, t = threadIdx.x;
  int b = t >> 3, ug = t & 7;
  const float4 h0 = *(const float4*)(hx + (size_t)b*HXS + n*64 + ug*8);
  const float4 h1 = *(const float4*)(hx + (size_t)b*HXS + n*64 + ug*8 + 4);
  uint4 o;
  o.x = pack2(h0.x, h0.y); o.y = pack2(h0.z, h0.w);
  o.z = pack2(h1.x, h1.y); o.w = pack2(h1.z, h1.w);
  ((uint4*)xs0_dw)[(((size_t)(b>>2)*NN + n)*4 + (b&3))*8 + ug] = o;
  if (t < 32){
    int bb = t;
    const float2 g = *(const float2*)(inputs + (size_t)bb*(NN*2) + n*2);
    unsigned int* xi = (unsigned int*)xsI4;
    xi[(((size_t)(bb>>2)*NN) + n)*4 + (bb&3)] = pack2(g.x, g.y);
  }
}

// ---------------- SpMM (sliced): slice = blockIdx&7 -> XCD-affine L2 working set ----------------
// 256 threads = 8 subgroups of 32 lanes; subgroup handles one node's edge list for this slice.
template<bool WITH_IN>
__global__ void k_spmm(const int* __restrict__ row_ptr, const int* __restrict__ col_s, const float* __restrict__ val_s,
                       uint4* xs4, uint4* xi4,
                       int supBase, int nsup, int srcA, int dstA, int srcB, int dstB){
  int s  = blockIdx.x & 7;
  int r2 = blockIdx.x >> 3;
  int supi = (nsup == 2 && r2 >= 1000) ? 1 : 0;
  int sup = supBase + supi;
  int g = r2 - supi*1000;
  int sub = threadIdx.x >> 5, lane = threadIdx.x & 31;
  int n = g*8 + sub;
  int msrc = supi ? srcB : srcA;
  int mdst = supi ? dstB : dstA;
  size_t srcS = (size_t)(msrc*8 + s)*SLAB4;
  size_t dstS = (size_t)(mdst*8 + s)*SLAB4;
  size_t srcI = (size_t)(msrc*8 + s)*NN;
  size_t dstI = (size_t)(mdst*8 + s)*NN;
  int beg = row_ptr[sup*(NN+1)+n], end = row_ptr[sup*(NN+1)+n+1];
  const int* cs = col_s + sup*EE;
  const float* vs = val_s + sup*EE;

  float a[8] = {0.f,0.f,0.f,0.f,0.f,0.f,0.f,0.f};
  float ai[8] = {0.f,0.f,0.f,0.f,0.f,0.f,0.f,0.f};
  for (int e = beg; e < end; ++e){
    int c = cs[e];
    float v = vs[e];
    uint4 q = xs4[srcS + (size_t)c*32 + lane];
    a[0]+=v*bflo(q.x); a[1]+=v*bfhi(q.x); a[2]+=v*bflo(q.y); a[3]+=v*bfhi(q.y);
    a[4]+=v*bflo(q.z); a[5]+=v*bfhi(q.z); a[6]+=v*bflo(q.w); a[7]+=v*bfhi(q.w);
    if (WITH_IN && lane == 0){
      uint4 qi = xi4[srcI + c];
      ai[0]+=v*bflo(qi.x); ai[1]+=v*bfhi(qi.x); ai[2]+=v*bflo(qi.y); ai[3]+=v*bfhi(qi.y);
      ai[4]+=v*bflo(qi.z); ai[5]+=v*bfhi(qi.z); ai[6]+=v*bflo(qi.w); ai[7]+=v*bfhi(qi.w);
    }
  }
  uint4 o;
  o.x = pack2(a[0],a[1]); o.y = pack2(a[2],a[3]); o.z = pack2(a[4],a[5]); o.w = pack2(a[6],a[7]);
  xs4[dstS + (size_t)n*32 + lane] = o;
  if (WITH_IN && lane == 0){
    uint4 oi;
    oi.x = pack2(ai[0],ai[1]); oi.y = pack2(ai[2],ai[3]); oi.z = pack2(ai[4],ai[5]); oi.w = pack2(ai[6],ai[7]);
    xi4[dstI + n] = oi;
  }
}

// ---------------- fused GEMM: dbuf LDS + global_load_lds + 2-phase pipeline ----------------
template<int NCOL, bool IS_RU>
__global__ __launch_bounds__(256) void k_gemm(const unsigned short* xsS,            // sliced slabs
                                              const unsigned int* __restrict__ xsI, // sliced dwords
                                              const unsigned short* __restrict__ Wt,// [NCOL][KP] bf16
                                              const float* __restrict__ bias,
                                              const float* __restrict__ hx,
                                              float* cout,
                                              unsigned short* ubuf){
  constexpr int CF = NCOL / 16;
  __shared__ unsigned short Al[2][128*64];
  __shared__ unsigned short Bl[2][NCOL*64];
  const int t = threadIdx.x;
  const int wv = t >> 6;
  const int l = t & 63;
  const int lr = l & 15;
  const int lg = l >> 4;
  const int R0 = blockIdx.x * 128;

  f32x4 acc[2][CF];
  const f32x4 zero = {0.f, 0.f, 0.f, 0.f};
  #pragma unroll
  for (int rf=0; rf<2; rf++)
    #pragma unroll
    for (int cf=0; cf<CF; cf++) acc[rf][cf] = zero;

  auto stageA = [&](int m, int buf){
    #pragma unroll
    for (int i=0;i<4;i++){
      int base = wv*256 + i*64;
      int slot = base + l;
      int r = slot >> 3, c = slot & 7;
      int row = R0 + r; int n = row >> 5, b = row & 31;
      const unsigned short* gp = xsS + ((((size_t)m*8 + (b>>2))*NN + n)*4 + (b&3))*64 + ((c ^ (r&7)) << 3);
      stage16(gp, &Al[buf][base*8], l);
    }
  };
  auto stageB = [&](int m, int buf){
    #pragma unroll
    for (int i=0;i<NCOL*8/256;i++){
      int base = i*256 + wv*64;
      int slot = base + l;
      int r = slot >> 3, c = slot & 7;
      const unsigned short* gp = Wt + (size_t)r*KP + m*64 + ((c ^ (r&7)) << 3);
      stage16(gp, &Bl[buf][base*8], l);
    }
  };

  stageA(0, 0); stageB(0, 0);
  asm volatile("s_waitcnt vmcnt(0)" ::: "memory");
  __syncthreads();

  #pragma unroll
  for (int m=0; m<5; m++){
    int cur = m & 1;
    if (m < 4){ stageA(m+1, cur^1); stageB(m+1, cur^1); }
    #pragma unroll
    for (int ks=0; ks<2; ks++){
      bf16x8 af[2];
      #pragma unroll
      for (int rf=0; rf<2; rf++){
        int row = wv*32 + rf*16 + lr;
        int chunk = (ks*4 + lg) ^ (row & 7);
        af[rf] = __builtin_bit_cast(bf16x8, *(const uint4*)(&Al[cur][row*64 + chunk*8]));
      }
      #pragma unroll
      for (int cf=0; cf<CF; cf++){
        int col = cf*16 + lr;
        int chunk = (ks*4 + lg) ^ (col & 7);
        bf16x8 bv = __builtin_bit_cast(bf16x8, *(const uint4*)(&Bl[cur][col*64 + chunk*8]));
        acc[0][cf] = __builtin_amdgcn_mfma_f32_16x16x32_bf16(af[0], bv, acc[0][cf], 0, 0, 0);
        acc[1][cf] = __builtin_amdgcn_mfma_f32_16x16x32_bf16(af[1], bv, acc[1][cf], 0, 0, 0);
      }
    }
    asm volatile("s_waitcnt vmcnt(0)" ::: "memory");
    __syncthreads();
  }

  // remainder K-step: input features (k 320..329 real), register fragments
  {
    bf16x8 af[2];
    #pragma unroll
    for (int rf=0; rf<2; rf++){
      int rg = R0 + wv*32 + rf*16 + lr;
      int n = rg >> 5, b = rg & 31;
      int s = b >> 2, bin = b & 3;
      unsigned int q0=0u,q1=0u,q2=0u,q3=0u;
      if (lg == 0){
        q0 = xsI[(((size_t)0*8+s)*NN+n)*4+bin];
        q1 = xsI[(((size_t)1*8+s)*NN+n)*4+bin];
        q2 = xsI[(((size_t)2*8+s)*NN+n)*4+bin];
        q3 = xsI[(((size_t)3*8+s)*NN+n)*4+bin];
      } else if (lg == 1){
        q0 = xsI[(((size_t)4*8+s)*NN+n)*4+bin];
      }
      uint4 qq; qq.x=q0; qq.y=q1; qq.z=q2; qq.w=q3;
      af[rf] = __builtin_bit_cast(bf16x8, qq);
    }
    #pragma unroll
    for (int cf=0; cf<CF; cf++){
      const uint4* p = (const uint4*)(Wt + (size_t)(cf*16 + lr)*KP + 320 + lg*8);
      bf16x8 bv = __builtin_bit_cast(bf16x8, *p);
      acc[0][cf] = __builtin_amdgcn_mfma_f32_16x16x32_bf16(af[0], bv, acc[0][cf], 0, 0, 0);
      acc[1][cf] = __builtin_amdgcn_mfma_f32_16x16x32_bf16(af[1], bv, acc[1][cf], 0, 0, 0);
    }
  }

  // epilogue: C/D layout col=lane&15, row=(lane>>4)*4+reg
  unsigned short* xs0w = (unsigned short*)xsS;  // slab m=0 (r*hx write target)
  #pragma unroll
  for (int rf=0; rf<2; rf++){
    #pragma unroll
    for (int reg=0; reg<4; reg++){
      int row = R0 + wv*32 + rf*16 + (lg << 2) + reg;
      int n = row >> 5, b = row & 31;
      int s = b >> 2, bin = b & 3;
      size_t rowoff = (size_t)b*HXS + (size_t)n*UU;
      size_t slot0 = (((size_t)s*NN + n)*4 + bin)*64;
      #pragma unroll
      for (int cf=0; cf<CF; cf++){
        int col = cf*16 + lr;
        float v = acc[rf][cf][reg] + bias[col];
        if constexpr (IS_RU){
          float sg = 1.f / (1.f + __expf(-v));
          if (cf < 4){ // r gate: r*hx (bf16 hx from xs0), written in place
            float h = bfu(xsS[slot0 + col]);
            xs0w[slot0 + col] = f2bf(sg * h);
          } else {     // u gate
            ubuf[rowoff + (col - 64)] = f2bf(sg);
          }
        } else {
          float cc = tanhf(v);
          float uu = bfu(ubuf[rowoff + col]);
          float h  = hx[rowoff + col];
          cout[rowoff + col] = uu*h + (1.f - uu)*cc;
        }
      }
    }
  }
}

// ---------------- launcher ----------------
extern "C" void kernel_launch(void* const* d_in, const int* in_sizes, int n_in,
                              void* d_out, int out_size, void* d_ws, size_t ws_size,
                              hipStream_t stream){
  const float* inputs = (const float*)d_in[0];
  const float* hx     = (const float*)d_in[1];
  const int*   row0   = (const int*)d_in[2];
  const int*   col0   = (const int*)d_in[3];
  const float* val0   = (const float*)d_in[4];
  const int*   row1   = (const int*)d_in[5];
  const int*   col1   = (const int*)d_in[6];
  const float* val1   = (const float*)d_in[7];
  const float* W_ru   = (const float*)d_in[8];
  const float* b_ru   = (const float*)d_in[9];
  const float* W_c    = (const float*)d_in[10];
  const float* b_c    = (const float*)d_in[11];
  float* out = (float*)d_out;

  char* ws = (char*)d_ws;
  size_t off = 0;
  auto alloc = [&](size_t bytes) -> void* {
    void* p = ws + off;
    off += (bytes + 255) & ~(size_t)255;
    return p;
  };
  unsigned short* xsS   = (unsigned short*)alloc((size_t)5*8*SLAB*2); // 163.84 MB
  unsigned int*   xsI   = (unsigned int*)  alloc((size_t)5*8*NN*16);  //   5.12 MB
  unsigned short* u_buf = (unsigned short*)alloc((size_t)NB*64*2);    //  32.77 MB
  unsigned short* Wru_t = (unsigned short*)alloc(128*KP*2);
  unsigned short* Wc_t  = (unsigned short*)alloc(64*KP*2);
  int*   row_ptr = (int*)  alloc(2*(NN+1)*4);
  int*   col_s   = (int*)  alloc(2*EE*4);
  float* val_s   = (float*)alloc(2*EE*4);
  int*   cnt     = (int*)  alloc(2*NN*4);
  int*   rp_work = (int*)  alloc(2*NN*4);
  (void)ws_size; (void)in_sizes; (void)n_in; (void)out_size;

  hipMemsetAsync(cnt, 0, 2*NN*4, stream);
  k_hist<<<(2*EE + 255)/256, 256, 0, stream>>>(row0, row1, cnt);
  k_scan<<<2, 1024, 0, stream>>>(cnt, row_ptr, rp_work);
  k_scatter<<<(2*EE + 255)/256, 256, 0, stream>>>(row0, col0, val0, row1, col1, val1, rp_work, col_s, val_s);
  k_wpack<<<(KP*192)/256, 256, 0, stream>>>(W_ru, W_c, Wru_t, Wc_t);
  k_x0<<<NN, 256, 0, stream>>>(inputs, hx, (unsigned int*)xsS, (uint4*)xsI);

  uint4* xs4 = (uint4*)xsS;
  uint4* xi4 = (uint4*)xsI;

  // gconv 1: hop1 merged (both supports read xs0), hop2 per support
  k_spmm<true ><<<16000, 256, 0, stream>>>(row_ptr, col_s, val_s, xs4, xi4, 0, 2, 0, 1, 0, 3);
  k_spmm<true ><<<8000, 256, 0, stream>>>(row_ptr, col_s, val_s, xs4, xi4, 0, 1, 1, 2, 0, 0);
  k_spmm<true ><<<8000, 256, 0, stream>>>(row_ptr, col_s, val_s, xs4, xi4, 1, 1, 3, 4, 0, 0);
  k_gemm<128, true><<<NB/128, 256, 0, stream>>>(xsS, xsI, Wru_t, b_ru, hx, nullptr, u_buf);

  // gconv 2: state part = r*hx (in xs0 slabs); input diffusion reused
  k_spmm<false><<<16000, 256, 0, stream>>>(row_ptr, col_s, val_s, xs4, xi4, 0, 2, 0, 1, 0, 3);
  k_spmm<false><<<8000, 256, 0, stream>>>(row_ptr, col_s, val_s, xs4, xi4, 0, 1, 1, 2, 0, 0);
  k_spmm<false><<<8000, 256, 0, stream>>>(row_ptr, col_s, val_s, xs4, xi4, 1, 1, 3, 4, 0, 0);
  k_gemm<64, false><<<NB/128, 256, 0, stream>>>(xsS, xsI, Wc_t, b_c, hx, out, u_buf);
}

// Round 4
// 510.238 us; speedup vs baseline: 1.1319x; 1.0136x over previous
//
#include <hip/hip_runtime.h>
#include <stdint.h>

#define NN 8000            // nodes
#define UU 64              // units
#define EE 64000           // edges per support
#define BB 32              // batch
#define NB 256000          // NN*BB rows of the logical GEMM
#define KP 352             // padded K (5*64 state + tail 32)
#define HXS 512000         // NN*UU (per-batch stride in hx)
#define SLAB4 256000       // NN*32 uint4 per (matrix,slice) slab

typedef __attribute__((ext_vector_type(8))) __bf16 bf16x8;
typedef __attribute__((ext_vector_type(4))) float f32x4;

__device__ __forceinline__ unsigned short f2bf(float f){
  unsigned int u = __builtin_bit_cast(unsigned int, f);
  u += 0x7fffu + ((u >> 16) & 1u);
  return (unsigned short)(u >> 16);
}
__device__ __forceinline__ unsigned int pack2(float a, float b){
  return (unsigned int)f2bf(a) | ((unsigned int)f2bf(b) << 16);
}
__device__ __forceinline__ float bflo(unsigned int w){ return __builtin_bit_cast(float, w << 16); }
__device__ __forceinline__ float bfhi(unsigned int w){ return __builtin_bit_cast(float, w & 0xffff0000u); }
__device__ __forceinline__ float bfu(unsigned short v){ return __builtin_bit_cast(float, (unsigned int)v << 16); }

__device__ __forceinline__ void acc8(float* a, float v, uint4 q){
  a[0]+=v*bflo(q.x); a[1]+=v*bfhi(q.x); a[2]+=v*bflo(q.y); a[3]+=v*bfhi(q.y);
  a[4]+=v*bflo(q.z); a[5]+=v*bfhi(q.z); a[6]+=v*bflo(q.w); a[7]+=v*bfhi(q.w);
}

// ---------------- CSR build ----------------
__global__ void k_hist(const int* __restrict__ r0, const int* __restrict__ r1, int* __restrict__ cnt){
  int i = blockIdx.x * 256 + threadIdx.x;
  if (i < 2*EE){
    int s = (i >= EE);
    int r = s ? r1[i - EE] : r0[i];
    atomicAdd(&cnt[s*NN + r], 1);
  }
}

__global__ __launch_bounds__(1024) void k_scan(const int* __restrict__ cnt, int* __restrict__ row_ptr, int* __restrict__ rp_work){
  int sup = blockIdx.x;
  const int* c = cnt + sup*NN;
  __shared__ int part[1024];
  int t = threadIdx.x;
  int loc[8]; int s = 0;
  #pragma unroll
  for (int j=0;j<8;j++){ int idx=t*8+j; int v = (idx<NN)? c[idx]:0; loc[j]=s; s+=v; }
  part[t]=s; __syncthreads();
  for (int o=1;o<1024;o<<=1){
    int v = (t>=o)? part[t-o]:0;
    __syncthreads();
    part[t]+=v;
    __syncthreads();
  }
  int pre = (t>0)? part[t-1]:0;
  #pragma unroll
  for (int j=0;j<8;j++){ int idx=t*8+j; if(idx<NN){ int e=pre+loc[j]; row_ptr[sup*(NN+1)+idx]=e; rp_work[sup*NN+idx]=e; } }
  if (t==1023) row_ptr[sup*(NN+1)+NN] = part[1023];
}

__global__ void k_scatter(const int* __restrict__ r0, const int* __restrict__ c0, const float* __restrict__ v0,
                          const int* __restrict__ r1, const int* __restrict__ c1, const float* __restrict__ v1,
                          int* __restrict__ rp_work, int* __restrict__ col_s, float* __restrict__ val_s){
  int i = blockIdx.x * 256 + threadIdx.x;
  if (i < 2*EE){
    int s = (i >= EE);
    int e = s ? i - EE : i;
    int r  = s ? r1[e] : r0[e];
    int cc = s ? c1[e] : c0[e];
    float vv = s ? v1[e] : v0[e];
    int pos = atomicAdd(&rp_work[s*NN + r], 1);
    col_s[s*EE + pos] = cc;
    val_s[s*EE + pos] = vv;
  }
}

// ---------------- weight repack (Chebyshev absorbed) ----------------
// Wp layout: m in 0..4: [m][col][64k] contiguous ; tail: base 320*ld + [col][32k]
__global__ void k_wpack(const float* __restrict__ W_ru, const float* __restrict__ W_c,
                        unsigned short* __restrict__ Wru_t, unsigned short* __restrict__ Wc_t){
  int i = blockIdx.x * 256 + threadIdx.x;   // 352*192 total
  int k = i / 192; int oo = i % 192;
  const float* W; int ld; unsigned short* dst; int o;
  if (oo < 128){ W = W_ru; ld = 128; dst = Wru_t; o = oo; }
  else         { W = W_c;  ld = 64;  dst = Wc_t;  o = oo - 128; }
  float v = 0.f;
  if (k < 330){
    int m, fb;
    if (k < 320){ m = k >> 6; fb = (2 + (k & 63)) * 5; }
    else        { int j = k - 320; m = j >> 1; fb = (j & 1) * 5; }
    if      (m==0) v = W[(fb+0)*ld+o] - W[(fb+2)*ld+o] - W[(fb+4)*ld+o];
    else if (m==1) v = W[(fb+1)*ld+o];
    else if (m==2) v = 2.f*W[(fb+2)*ld+o];
    else if (m==3) v = W[(fb+3)*ld+o];
    else           v = 2.f*W[(fb+4)*ld+o];
  }
  int dstoff;
  if (k < 320) dstoff = (k>>6)*ld*64 + o*64 + (k&63);
  else         dstoff = 320*ld + o*32 + (k-320);
  dst[dstoff] = f2bf(v);
}

// ---------------- build x0 (transpose + bf16, batch-sliced slabs) ----------------
// xsS slab(m,s): [NN][4 bin][64 u] bf16 ; xsI slab(m,s): [NN] uint4
__global__ void k_x0(const float* __restrict__ inputs, const float* __restrict__ hx,
                     uint4* __restrict__ xs0q, unsigned int* __restrict__ xi0){
  int n = blockIdx.x, t = threadIdx.x;
  int b = t >> 3, ug = t & 7;
  const float4 h0 = *(const float4*)(hx + (size_t)b*HXS + n*64 + ug*8);
  const float4 h1 = *(const float4*)(hx + (size_t)b*HXS + n*64 + ug*8 + 4);
  uint4 o;
  o.x = pack2(h0.x, h0.y); o.y = pack2(h0.z, h0.w);
  o.z = pack2(h1.x, h1.y); o.w = pack2(h1.z, h1.w);
  xs0q[(((size_t)(b>>2)*NN + n)*4 + (b&3))*8 + ug] = o;
  if (t < 32){
    int bb = t;
    const float2 g = *(const float2*)(inputs + (size_t)bb*(NN*2) + n*2);
    xi0[(((size_t)(bb>>2)*NN) + n)*4 + (bb&3)] = pack2(g.x, g.y);
  }
}

// ---------------- SpMM (sliced, 4-deep pipelined) ----------------
// state blocks: 16000 = 8 slices x 2 sups x 1000 groups of 8 nodes (32 lanes each)
// WITH_IN: +512 blocks handle the tiny input-feature diffusion, 1 node/lane
template<bool WITH_IN>
__global__ void k_spmm(const int* __restrict__ row_ptr, const int* __restrict__ col_s, const float* __restrict__ val_s,
                       uint4* xs4, uint4* xi4,
                       int srcA, int dstA, int srcB, int dstB){
  int bid = blockIdx.x;
  if (WITH_IN && bid >= 16000){
    int b2 = bid - 16000;
    int s = b2 & 7, supi = (b2 >> 3) & 1, chunk = b2 >> 4;
    int n = chunk*256 + threadIdx.x;
    if (n >= NN) return;
    int msrc = supi ? srcB : srcA, mdst = supi ? dstB : dstA;
    size_t sb = (size_t)(msrc*8 + s)*NN, db = (size_t)(mdst*8 + s)*NN;
    int beg = row_ptr[supi*(NN+1)+n], end = row_ptr[supi*(NN+1)+n+1];
    const int* cs = col_s + supi*EE; const float* vs = val_s + supi*EE;
    float ai[8] = {0.f,0.f,0.f,0.f,0.f,0.f,0.f,0.f};
    for (int e = beg; e < end; ++e){
      int c = cs[e]; float v = vs[e];
      uint4 qi = xi4[sb + c];
      acc8(ai, v, qi);
    }
    uint4 oi;
    oi.x = pack2(ai[0],ai[1]); oi.y = pack2(ai[2],ai[3]); oi.z = pack2(ai[4],ai[5]); oi.w = pack2(ai[6],ai[7]);
    xi4[db + n] = oi;
    return;
  }
  int s  = bid & 7;
  int r2 = bid >> 3;
  int supi = (r2 >= 1000) ? 1 : 0;
  int g = r2 - supi*1000;
  int sub = threadIdx.x >> 5, lane = threadIdx.x & 31;
  int n = g*8 + sub;
  int msrc = supi ? srcB : srcA, mdst = supi ? dstB : dstA;
  size_t sS = (size_t)(msrc*8 + s)*SLAB4;
  size_t dS = (size_t)(mdst*8 + s)*SLAB4;
  int beg = row_ptr[supi*(NN+1)+n], end = row_ptr[supi*(NN+1)+n+1];
  const int* cs = col_s + supi*EE;
  const float* vs = val_s + supi*EE;

  float a[8] = {0.f,0.f,0.f,0.f,0.f,0.f,0.f,0.f};
  int e = beg;
  for (; e + 4 <= end; e += 4){
    int c0=cs[e], c1=cs[e+1], c2=cs[e+2], c3=cs[e+3];
    float v0=vs[e], v1=vs[e+1], v2=vs[e+2], v3=vs[e+3];
    uint4 q0 = xs4[sS + (size_t)c0*32 + lane];
    uint4 q1 = xs4[sS + (size_t)c1*32 + lane];
    uint4 q2 = xs4[sS + (size_t)c2*32 + lane];
    uint4 q3 = xs4[sS + (size_t)c3*32 + lane];
    acc8(a, v0, q0); acc8(a, v1, q1); acc8(a, v2, q2); acc8(a, v3, q3);
  }
  for (; e < end; ++e){
    int c = cs[e]; float v = vs[e];
    uint4 q = xs4[sS + (size_t)c*32 + lane];
    acc8(a, v, q);
  }
  uint4 o;
  o.x = pack2(a[0],a[1]); o.y = pack2(a[2],a[3]); o.z = pack2(a[4],a[5]); o.w = pack2(a[6],a[7]);
  xs4[dS + (size_t)n*32 + lane] = o;
}

// ---------------- fused GEMM: A fully register-prefetched, B direct from L2, no LDS ----------------
template<int NCOL, bool IS_RU>
__global__ __launch_bounds__(256) void k_gemm(const unsigned short* xsS,             // sliced slabs (also r*hx write target)
                                              const unsigned int* __restrict__ xsI,  // sliced input dwords
                                              const unsigned short* __restrict__ Wp, // packed [m][NCOL][64] + tail [NCOL][32]
                                              const float* __restrict__ bias,
                                              const float* __restrict__ hx,
                                              float* cout,
                                              unsigned short* ubuf){
  constexpr int CF = NCOL / 16;
  const int t = threadIdx.x;
  const int wv = t >> 6;
  const int l = t & 63;
  const int lr = l & 15;
  const int lg = l >> 4;
  const int R0 = blockIdx.x * 128;

  // ---- burst-issue ALL A loads (20 state frags + tail) ----
  size_t rbase[2];
  #pragma unroll
  for (int rf=0; rf<2; rf++){
    int row = R0 + wv*32 + rf*16 + lr;
    int n = row >> 5, b = row & 31, s = b >> 2, bin = b & 3;
    rbase[rf] = (((size_t)s*NN + n)*4 + bin)*64;
  }
  uint4 aA[5][2][2];
  #pragma unroll
  for (int m=0; m<5; m++)
    #pragma unroll
    for (int ks=0; ks<2; ks++)
      #pragma unroll
      for (int rf=0; rf<2; rf++)
        aA[m][ks][rf] = *(const uint4*)(xsS + (size_t)m*8*NN*256 + rbase[rf] + ks*32 + lg*8);
  uint4 aT[2];
  #pragma unroll
  for (int rf=0; rf<2; rf++){
    size_t ib = rbase[rf] >> 6;     // ((s*NN+n)*4+bin)
    unsigned int q0=0u,q1=0u,q2=0u,q3=0u;
    if (lg == 0){
      q0 = xsI[ib];
      q1 = xsI[(size_t)8*NN*4 + ib];
      q2 = xsI[(size_t)16*NN*4 + ib];
      q3 = xsI[(size_t)24*NN*4 + ib];
    } else if (lg == 1){
      q0 = xsI[(size_t)32*NN*4 + ib];
    }
    uint4 qq; qq.x=q0; qq.y=q1; qq.z=q2; qq.w=q3;
    aT[rf] = qq;
  }
  __builtin_amdgcn_sched_barrier(0);

  f32x4 acc[2][CF];
  const f32x4 zero = {0.f, 0.f, 0.f, 0.f};
  #pragma unroll
  for (int rf=0; rf<2; rf++)
    #pragma unroll
    for (int cf=0; cf<CF; cf++) acc[rf][cf] = zero;

  // ---- MFMA chain, B fragments direct from L2 (dense packed rows) ----
  #pragma unroll
  for (int m=0; m<5; m++){
    #pragma unroll
    for (int ks=0; ks<2; ks++){
      #pragma unroll
      for (int cf=0; cf<CF; cf++){
        const uint4* p = (const uint4*)(Wp + ((size_t)m*NCOL + cf*16 + lr)*64 + ks*32 + lg*8);
        bf16x8 bv = __builtin_bit_cast(bf16x8, *p);
        acc[0][cf] = __builtin_amdgcn_mfma_f32_16x16x32_bf16(__builtin_bit_cast(bf16x8, aA[m][ks][0]), bv, acc[0][cf], 0, 0, 0);
        acc[1][cf] = __builtin_amdgcn_mfma_f32_16x16x32_bf16(__builtin_bit_cast(bf16x8, aA[m][ks][1]), bv, acc[1][cf], 0, 0, 0);
      }
    }
  }
  #pragma unroll
  for (int cf=0; cf<CF; cf++){
    const uint4* p = (const uint4*)(Wp + (size_t)NCOL*320 + (cf*16 + lr)*32 + lg*8);
    bf16x8 bv = __builtin_bit_cast(bf16x8, *p);
    acc[0][cf] = __builtin_amdgcn_mfma_f32_16x16x32_bf16(__builtin_bit_cast(bf16x8, aT[0]), bv, acc[0][cf], 0, 0, 0);
    acc[1][cf] = __builtin_amdgcn_mfma_f32_16x16x32_bf16(__builtin_bit_cast(bf16x8, aT[1]), bv, acc[1][cf], 0, 0, 0);
  }

  // ---- epilogue: C/D layout col=lane&15, row=(lane>>4)*4+reg ----
  unsigned short* xs0w = (unsigned short*)xsS;  // slab m=0 (r*hx write target)
  #pragma unroll
  for (int rf=0; rf<2; rf++){
    #pragma unroll
    for (int reg=0; reg<4; reg++){
      int row = R0 + wv*32 + rf*16 + (lg << 2) + reg;
      int n = row >> 5, b = row & 31;
      int s = b >> 2, bin = b & 3;
      size_t rowoff = (size_t)b*HXS + (size_t)n*UU;
      size_t slot0 = (((size_t)s*NN + n)*4 + bin)*64;
      #pragma unroll
      for (int cf=0; cf<CF; cf++){
        int col = cf*16 + lr;
        float v = acc[rf][cf][reg] + bias[col];
        if constexpr (IS_RU){
          float sg = 1.f / (1.f + __expf(-v));
          if (cf < 4){ // r gate: r*hx (bf16 hx from xs0), written in place
            float h = bfu(((const unsigned short*)xsS)[slot0 + col]);
            xs0w[slot0 + col] = f2bf(sg * h);
          } else {     // u gate
            ubuf[rowoff + (col - 64)] = f2bf(sg);
          }
        } else {
          float cc = tanhf(v);
          float uu = bfu(ubuf[rowoff + col]);
          float h  = hx[rowoff + col];
          cout[rowoff + col] = uu*h + (1.f - uu)*cc;
        }
      }
    }
  }
}

// ---------------- launcher ----------------
extern "C" void kernel_launch(void* const* d_in, const int* in_sizes, int n_in,
                              void* d_out, int out_size, void* d_ws, size_t ws_size,
                              hipStream_t stream){
  const float* inputs = (const float*)d_in[0];
  const float* hx     = (const float*)d_in[1];
  const int*   row0   = (const int*)d_in[2];
  const int*   col0   = (const int*)d_in[3];
  const float* val0   = (const float*)d_in[4];
  const int*   row1   = (const int*)d_in[5];
  const int*   col1   = (const int*)d_in[6];
  const float* val1   = (const float*)d_in[7];
  const float* W_ru   = (const float*)d_in[8];
  const float* b_ru   = (const float*)d_in[9];
  const float* W_c    = (const float*)d_in[10];
  const float* b_c    = (const float*)d_in[11];
  float* out = (float*)d_out;

  char* ws = (char*)d_ws;
  size_t off = 0;
  auto alloc = [&](size_t bytes) -> void* {
    void* p = ws + off;
    off += (bytes + 255) & ~(size_t)255;
    return p;
  };
  unsigned short* xsS   = (unsigned short*)alloc((size_t)5*8*NN*256*2); // 163.84 MB
  unsigned int*   xsI   = (unsigned int*)  alloc((size_t)5*8*NN*16);    //   5.12 MB
  unsigned short* u_buf = (unsigned short*)alloc((size_t)NB*64*2);      //  32.77 MB
  unsigned short* Wru_t = (unsigned short*)alloc(128*KP*2);
  unsigned short* Wc_t  = (unsigned short*)alloc(64*KP*2);
  int*   row_ptr = (int*)  alloc(2*(NN+1)*4);
  int*   col_s   = (int*)  alloc(2*EE*4);
  float* val_s   = (float*)alloc(2*EE*4);
  int*   cnt     = (int*)  alloc(2*NN*4);
  int*   rp_work = (int*)  alloc(2*NN*4);
  (void)ws_size; (void)in_sizes; (void)n_in; (void)out_size;

  hipMemsetAsync(cnt, 0, 2*NN*4, stream);
  k_hist<<<(2*EE + 255)/256, 256, 0, stream>>>(row0, row1, cnt);
  k_scan<<<2, 1024, 0, stream>>>(cnt, row_ptr, rp_work);
  k_scatter<<<(2*EE + 255)/256, 256, 0, stream>>>(row0, col0, val0, row1, col1, val1, rp_work, col_s, val_s);
  k_wpack<<<(KP*192)/256, 256, 0, stream>>>(W_ru, W_c, Wru_t, Wc_t);
  k_x0<<<NN, 256, 0, stream>>>(inputs, hx, (uint4*)xsS, (unsigned int*)xsI);

  uint4* xs4 = (uint4*)xsS;
  uint4* xi4 = (uint4*)xsI;

  // gconv 1: hop1 (both supports, + input blocks), hop2 (both supports, + input blocks)
  k_spmm<true ><<<16512, 256, 0, stream>>>(row_ptr, col_s, val_s, xs4, xi4, 0, 1, 0, 3);
  k_spmm<true ><<<16512, 256, 0, stream>>>(row_ptr, col_s, val_s, xs4, xi4, 1, 2, 3, 4);
  k_gemm<128, true><<<NB/128, 256, 0, stream>>>(xsS, xsI, Wru_t, b_ru, hx, nullptr, u_buf);

  // gconv 2: state part = r*hx (in xs0 slabs); input diffusion reused from gconv1
  k_spmm<false><<<16000, 256, 0, stream>>>(row_ptr, col_s, val_s, xs4, xi4, 0, 1, 0, 3);
  k_spmm<false><<<16000, 256, 0, stream>>>(row_ptr, col_s, val_s, xs4, xi4, 1, 2, 3, 4);
  k_gemm<64, false><<<NB/128, 256, 0, stream>>>(xsS, xsI, Wc_t, b_c, hx, out, u_buf);
}

// Round 6
// 428.599 us; speedup vs baseline: 1.3475x; 1.1905x over previous
//
#include <hip/hip_runtime.h>
#include <stdint.h>

#define NN 8000            // nodes
#define UU 64              // units
#define EE 64000           // edges per support
#define BB 32              // batch
#define NB 256000          // NN*BB rows of the logical GEMM
#define HXS 512000         // NN*UU (per-batch stride in hx)
#define SLAB4 256000       // NN*32 uint4 per (matrix,slice) slab
#define NT 8               // row-tiles per persistent GEMM block (2000/250)

typedef __attribute__((ext_vector_type(8))) __bf16 bf16x8;
typedef __attribute__((ext_vector_type(4))) float f32x4;

__device__ __forceinline__ unsigned short f2bf(float f){
  unsigned int u = __builtin_bit_cast(unsigned int, f);
  u += 0x7fffu + ((u >> 16) & 1u);
  return (unsigned short)(u >> 16);
}
__device__ __forceinline__ unsigned int pack2(float a, float b){
  return (unsigned int)f2bf(a) | ((unsigned int)f2bf(b) << 16);
}
__device__ __forceinline__ float bflo(unsigned int w){ return __builtin_bit_cast(float, w << 16); }
__device__ __forceinline__ float bfhi(unsigned int w){ return __builtin_bit_cast(float, w & 0xffff0000u); }
__device__ __forceinline__ float bfu(unsigned short v){ return __builtin_bit_cast(float, (unsigned int)v << 16); }

__device__ __forceinline__ void acc8(float* a, float v, uint4 q){
  a[0]+=v*bflo(q.x); a[1]+=v*bfhi(q.x); a[2]+=v*bflo(q.y); a[3]+=v*bfhi(q.y);
  a[4]+=v*bflo(q.z); a[5]+=v*bfhi(q.z); a[6]+=v*bflo(q.w); a[7]+=v*bfhi(q.w);
}

// async global->LDS, 16B per lane; LDS dest = uniform base + lane*16 (linear).
__device__ __forceinline__ void stage16(const unsigned short* g, unsigned short* ldsbase){
  __builtin_amdgcn_global_load_lds((const __attribute__((address_space(1))) void*)g,
                                   (__attribute__((address_space(3))) void*)ldsbase, 16, 0, 0);
}

// ---------------- CSR build ----------------
__global__ void k_hist(const int* __restrict__ r0, const int* __restrict__ r1, int* __restrict__ cnt){
  int i = blockIdx.x * 256 + threadIdx.x;
  if (i < 2*EE){
    int s = (i >= EE);
    int r = s ? r1[i - EE] : r0[i];
    atomicAdd(&cnt[s*NN + r], 1);
  }
}

__global__ __launch_bounds__(1024) void k_scan(const int* __restrict__ cnt, int* __restrict__ row_ptr, int* __restrict__ rp_work){
  int sup = blockIdx.x;
  const int* c = cnt + sup*NN;
  __shared__ int part[1024];
  int t = threadIdx.x;
  int loc[8]; int s = 0;
  #pragma unroll
  for (int j=0;j<8;j++){ int idx=t*8+j; int v = (idx<NN)? c[idx]:0; loc[j]=s; s+=v; }
  part[t]=s; __syncthreads();
  for (int o=1;o<1024;o<<=1){
    int v = (t>=o)? part[t-o]:0;
    __syncthreads();
    part[t]+=v;
    __syncthreads();
  }
  int pre = (t>0)? part[t-1]:0;
  #pragma unroll
  for (int j=0;j<8;j++){ int idx=t*8+j; if(idx<NN){ int e=pre+loc[j]; row_ptr[sup*(NN+1)+idx]=e; rp_work[sup*NN+idx]=e; } }
  if (t==1023) row_ptr[sup*(NN+1)+NN] = part[1023];
}

__global__ void k_scatter(const int* __restrict__ r0, const int* __restrict__ c0, const float* __restrict__ v0,
                          const int* __restrict__ r1, const int* __restrict__ c1, const float* __restrict__ v1,
                          int* __restrict__ rp_work, int* __restrict__ col_s, float* __restrict__ val_s){
  int i = blockIdx.x * 256 + threadIdx.x;
  if (i < 2*EE){
    int s = (i >= EE);
    int e = s ? i - EE : i;
    int r  = s ? r1[e] : r0[e];
    int cc = s ? c1[e] : c0[e];
    float vv = s ? v1[e] : v0[e];
    int pos = atomicAdd(&rp_work[s*NN + r], 1);
    col_s[s*EE + pos] = cc;
    val_s[s*EE + pos] = vv;
  }
}

// ---------------- weight repack (Chebyshev absorbed, column-permuted) ----------------
// GEMM col c -> output unit o = 4*(c&15) + ((c>>4)&3); r/u block kept by c<64.
// Wp layout: m 0..4: [m][NCOL][64k] ; tail at 320*NCOL: [NCOL][32k]
__global__ void k_wpack(const float* __restrict__ W_ru, const float* __restrict__ W_c,
                        unsigned short* __restrict__ Wru_t, unsigned short* __restrict__ Wc_t){
  int i = blockIdx.x * 256 + threadIdx.x;   // 352*192 total
  int k = i / 192; int oo = i % 192;
  const float* W; int ld, NC; unsigned short* dst; int c;
  if (oo < 128){ W = W_ru; ld = 128; NC = 128; dst = Wru_t; c = oo; }
  else         { W = W_c;  ld = 64;  NC = 64;  dst = Wc_t;  c = oo - 128; }
  int o = 4*(c & 15) + ((c >> 4) & 3);
  int wcol = (c >= 64) ? 64 + o : o;
  float v = 0.f;
  if (k < 330){
    int m, fb;
    if (k < 320){ m = k >> 6; fb = (2 + (k & 63)) * 5; }
    else        { int j = k - 320; m = j >> 1; fb = (j & 1) * 5; }
    if      (m==0) v = W[(fb+0)*ld+wcol] - W[(fb+2)*ld+wcol] - W[(fb+4)*ld+wcol];
    else if (m==1) v = W[(fb+1)*ld+wcol];
    else if (m==2) v = 2.f*W[(fb+2)*ld+wcol];
    else if (m==3) v = W[(fb+3)*ld+wcol];
    else           v = 2.f*W[(fb+4)*ld+wcol];
  }
  int dstoff;
  if (k < 320) dstoff = (k>>6)*NC*64 + c*64 + (k&63);
  else         dstoff = 320*NC + c*32 + (k-320);
  dst[dstoff] = f2bf(v);
}

// ---------------- build x0 (transpose + bf16, batch-sliced slabs) ----------------
__global__ void k_x0(const float* __restrict__ inputs, const float* __restrict__ hx,
                     uint4* __restrict__ xs0q, unsigned int* __restrict__ xi0){
  int n = blockIdx.x, t = threadIdx.x;
  int b = t >> 3, ug = t & 7;
  const float4 h0 = *(const float4*)(hx + (size_t)b*HXS + n*64 + ug*8);
  const float4 h1 = *(const float4*)(hx + (size_t)b*HXS + n*64 + ug*8 + 4);
  uint4 o;
  o.x = pack2(h0.x, h0.y); o.y = pack2(h0.z, h0.w);
  o.z = pack2(h1.x, h1.y); o.w = pack2(h1.z, h1.w);
  xs0q[(((size_t)(b>>2)*NN + n)*4 + (b&3))*8 + ug] = o;
  if (t < 32){
    int bb = t;
    const float2 g = *(const float2*)(inputs + (size_t)bb*(NN*2) + n*2);
    xi0[(((size_t)(bb>>2)*NN) + n)*4 + (bb&3)] = pack2(g.x, g.y);
  }
}

// ---------------- SpMM (sliced) ----------------
template<bool WITH_IN>
__global__ void k_spmm(const int* __restrict__ row_ptr, const int* __restrict__ col_s, const float* __restrict__ val_s,
                       uint4* xs4, uint4* xi4,
                       int srcA, int dstA, int srcB, int dstB){
  int bid = blockIdx.x;
  if (WITH_IN && bid >= 16000){
    int b2 = bid - 16000;
    int s = b2 & 7, supi = (b2 >> 3) & 1, chunk = b2 >> 4;
    int n = chunk*256 + threadIdx.x;
    if (n >= NN) return;
    int msrc = supi ? srcB : srcA, mdst = supi ? dstB : dstA;
    size_t sb = (size_t)(msrc*8 + s)*NN, db = (size_t)(mdst*8 + s)*NN;
    int beg = row_ptr[supi*(NN+1)+n], end = row_ptr[supi*(NN+1)+n+1];
    const int* cs = col_s + supi*EE; const float* vs = val_s + supi*EE;
    float ai[8] = {0.f,0.f,0.f,0.f,0.f,0.f,0.f,0.f};
    for (int e = beg; e < end; ++e){
      int c = cs[e]; float v = vs[e];
      uint4 qi = xi4[sb + c];
      acc8(ai, v, qi);
    }
    uint4 oi;
    oi.x = pack2(ai[0],ai[1]); oi.y = pack2(ai[2],ai[3]); oi.z = pack2(ai[4],ai[5]); oi.w = pack2(ai[6],ai[7]);
    xi4[db + n] = oi;
    return;
  }
  int s  = bid & 7;
  int r2 = bid >> 3;
  int supi = (r2 >= 1000) ? 1 : 0;
  int g = r2 - supi*1000;
  int sub = threadIdx.x >> 5, lane = threadIdx.x & 31;
  int n = g*8 + sub;
  int msrc = supi ? srcB : srcA, mdst = supi ? dstB : dstA;
  size_t sS = (size_t)(msrc*8 + s)*SLAB4;
  size_t dS = (size_t)(mdst*8 + s)*SLAB4;
  int beg = row_ptr[supi*(NN+1)+n], end = row_ptr[supi*(NN+1)+n+1];
  const int* cs = col_s + supi*EE;
  const float* vs = val_s + supi*EE;

  float a[8] = {0.f,0.f,0.f,0.f,0.f,0.f,0.f,0.f};
  int e = beg;
  for (; e + 4 <= end; e += 4){
    int c0=cs[e], c1=cs[e+1], c2=cs[e+2], c3=cs[e+3];
    float v0=vs[e], v1=vs[e+1], v2=vs[e+2], v3=vs[e+3];
    uint4 q0 = xs4[sS + (size_t)c0*32 + lane];
    uint4 q1 = xs4[sS + (size_t)c1*32 + lane];
    uint4 q2 = xs4[sS + (size_t)c2*32 + lane];
    uint4 q3 = xs4[sS + (size_t)c3*32 + lane];
    acc8(a, v0, q0); acc8(a, v1, q1); acc8(a, v2, q2); acc8(a, v3, q3);
  }
  for (; e < end; ++e){
    int c = cs[e]; float v = vs[e];
    uint4 q = xs4[sS + (size_t)c*32 + lane];
    acc8(a, v, q);
  }
  uint4 o;
  o.x = pack2(a[0],a[1]); o.y = pack2(a[2],a[3]); o.z = pack2(a[4],a[5]); o.w = pack2(a[6],a[7]);
  xs4[dS + (size_t)n*32 + lane] = o;
}

// ---------------- persistent-block GEMM: B resident in LDS, A through 4-slot ring, counted vmcnt ----------------
template<int NCOL, bool IS_RU>
__global__ __launch_bounds__(256) void k_gemm(unsigned short* xsS,                   // sliced slabs (slab0 = hx-bf16 / r*hx target)
                                              const unsigned int* __restrict__ xsI,  // sliced input dwords
                                              const unsigned short* __restrict__ Wp, // packed [m][NCOL][64] + tail [NCOL][32]
                                              const float* __restrict__ bias,
                                              const float* __restrict__ hx,
                                              float* cout,
                                              unsigned short* ubuf){
  constexpr int CF = NCOL / 16;
  constexpr int BCH = NCOL*44;             // B chunks of 16B: (5*NCOL*64 + NCOL*32)/8
  constexpr int BPT = BCH/256;             // per-thread B loads (22 / 11)
  constexpr int MCH = 5*NCOL*8;            // chunks in the 5 m-blocks
  __shared__ unsigned short ring[4][128*64];
  __shared__ unsigned short Bs[5*NCOL*64 + NCOL*32];

  const int t = threadIdx.x;
  const int wv = t >> 6;
  const int l = t & 63;
  const int lr = l & 15;
  const int lg = l >> 4;
  const int tile0 = blockIdx.x * NT;

  // ---- stage B once (linear dest, inverse-swizzled source) ----
  #pragma unroll
  for (int i=0;i<BPT;i++){
    int g = t + i*256;
    const unsigned short* gp;
    if (g < MCH){
      int rr = g >> 3, c = g & 7;
      gp = Wp + (size_t)rr*64 + ((c ^ (rr&7)) << 3);
    } else {
      int gt = g - MCH; int rr = gt >> 2, c = gt & 3;
      gp = Wp + (size_t)320*NCOL + rr*32 + ((c ^ (rr&3)) << 3);
    }
    stage16(gp, &Bs[(size_t)(i*256 + wv*64)*8]);
  }

  auto stageA = [&](int rt, int mm, int slot){
    int R0 = (tile0 + rt) << 7;
    #pragma unroll
    for (int i=0;i<4;i++){
      int base = wv*256 + i*64;
      int sl = base + l;
      int rr = sl >> 3, c = sl & 7;
      int row = R0 + rr; int n = row >> 5, b = row & 31;
      const unsigned short* gp = xsS + (size_t)mm*(8*NN*256)
          + ((((size_t)(b>>2))*NN + n)*4 + (b&3))*64 + ((c ^ (rr&7)) << 3);
      stage16(gp, &ring[slot][(size_t)base*8]);
    }
  };

  // prologue: tiles j=0,1,2
  stageA(0, 0, 0); stageA(0, 1, 1); stageA(0, 2, 2);

  f32x4 acc[2][CF];
  const f32x4 zero = {0.f,0.f,0.f,0.f};
  #pragma unroll
  for (int rf=0; rf<2; rf++)
    #pragma unroll
    for (int cf=0; cf<CF; cf++) acc[rf][cf] = zero;

  unsigned int q[2][5];
  size_t ib[2];

  #pragma unroll 1
  for (int r_=0; r_<NT; ++r_){
    int R0 = (tile0 + r_) << 7;
    #pragma unroll
    for (int m=0; m<5; ++m){
      // tail-fragment prefetch at m==0 (plain loads; compiler-managed waits)
      if (m == 0){
        #pragma unroll
        for (int rf=0; rf<2; rf++){
          int row = R0 + wv*32 + rf*16 + lr;
          int n = row >> 5, b = row & 31;
          ib[rf] = (((size_t)(b>>2))*NN + n)*4 + (b&3);
          #pragma unroll
          for (int mi=0; mi<5; mi++)
            q[rf][mi] = xsI[(size_t)mi*(8*NN*4) + ib[rf]];
        }
      }
      // counted wait: steady 8 (two tiles in flight); ramp down at the very end
      if (r_ == NT-1 && m == 3)      { asm volatile("s_waitcnt vmcnt(4)" ::: "memory"); }
      else if (r_ == NT-1 && m == 4) { asm volatile("s_waitcnt vmcnt(0)" ::: "memory"); }
      else                           { asm volatile("s_waitcnt vmcnt(8)" ::: "memory"); }
      __builtin_amdgcn_s_barrier();
      __builtin_amdgcn_sched_barrier(0);
      // stage tile j+3
      if (!(r_ == NT-1 && m >= 2)){
        int mm = (m+3 >= 5) ? m-2 : m+3;
        int rt = (m+3 >= 5) ? r_+1 : r_;
        stageA(rt, mm, (r_*5 + m + 3) & 3);
      }
      // compute tile j = r_*5+m
      const unsigned short* Alc = ring[(r_*5 + m) & 3];
      const unsigned short* Bm  = Bs + m*NCOL*64;
      #pragma unroll
      for (int ks=0; ks<2; ks++){
        bf16x8 af[2];
        #pragma unroll
        for (int rf=0; rf<2; rf++){
          int rr = wv*32 + rf*16 + lr;
          int chunk = (ks*4 + lg) ^ (rr & 7);
          af[rf] = __builtin_bit_cast(bf16x8, *(const uint4*)(Alc + rr*64 + chunk*8));
        }
        #pragma unroll
        for (int cf=0; cf<CF; cf++){
          int col = cf*16 + lr;
          int chunk = (ks*4 + lg) ^ (col & 7);
          bf16x8 bv = __builtin_bit_cast(bf16x8, *(const uint4*)(Bm + col*64 + chunk*8));
          acc[0][cf] = __builtin_amdgcn_mfma_f32_16x16x32_bf16(af[0], bv, acc[0][cf], 0, 0, 0);
          acc[1][cf] = __builtin_amdgcn_mfma_f32_16x16x32_bf16(af[1], bv, acc[1][cf], 0, 0, 0);
        }
      }
    }
    // ---- tail K-step (input features) ----
    {
      const unsigned short* Bt = Bs + 5*NCOL*64;
      bf16x8 af[2];
      #pragma unroll
      for (int rf=0; rf<2; rf++){
        uint4 qq;
        qq.x = (lg==0) ? q[rf][0] : ((lg==1) ? q[rf][4] : 0u);
        qq.y = (lg==0) ? q[rf][1] : 0u;
        qq.z = (lg==0) ? q[rf][2] : 0u;
        qq.w = (lg==0) ? q[rf][3] : 0u;
        af[rf] = __builtin_bit_cast(bf16x8, qq);
      }
      #pragma unroll
      for (int cf=0; cf<CF; cf++){
        int col = cf*16 + lr;
        int chunk = lg ^ (col & 3);
        bf16x8 bv = __builtin_bit_cast(bf16x8, *(const uint4*)(Bt + col*32 + chunk*8));
        acc[0][cf] = __builtin_amdgcn_mfma_f32_16x16x32_bf16(af[0], bv, acc[0][cf], 0, 0, 0);
        acc[1][cf] = __builtin_amdgcn_mfma_f32_16x16x32_bf16(af[1], bv, acc[1][cf], 0, 0, 0);
      }
    }
    // ---- epilogue (col c -> unit 4*lr+cf; vectorized 8B/16B stores) ----
    #pragma unroll
    for (int rf=0; rf<2; rf++){
      #pragma unroll
      for (int reg=0; reg<4; reg++){
        int row = R0 + wv*32 + rf*16 + (lg << 2) + reg;
        int n = row >> 5, b = row & 31;
        size_t rowoff = (size_t)b*HXS + (size_t)n*UU;
        size_t slot0 = ((((size_t)(b>>2))*NN + n)*4 + (b&3))*64;
        int o0 = lr << 2;
        if constexpr (IS_RU){
          uint2 hv = *(const uint2*)(xsS + slot0 + o0);   // hx bf16 (slab0, pre-overwrite)
          unsigned short rr4[4], uu4[4];
          #pragma unroll
          for (int cf=0; cf<4; cf++){
            int o = o0 + cf;
            float vr = acc[rf][cf][reg]   + bias[o];
            float vu = acc[rf][cf+4][reg] + bias[64+o];
            float sgr = 1.f/(1.f + __expf(-vr));
            float sgu = 1.f/(1.f + __expf(-vu));
            float h = bfu(((const unsigned short*)&hv)[cf]);
            rr4[cf] = f2bf(sgr * h);
            uu4[cf] = f2bf(sgu);
          }
          *(uint2*)(xsS + slot0 + o0) = *(uint2*)rr4;
          *(uint2*)(ubuf + rowoff + o0) = *(uint2*)uu4;
        } else {
          float4 hv = *(const float4*)(hx + rowoff + o0);
          uint2 uv = *(const uint2*)(ubuf + rowoff + o0);
          float4 ov;
          #pragma unroll
          for (int cf=0; cf<4; cf++){
            float cc = tanhf(acc[rf][cf][reg] + bias[o0+cf]);
            float uu = bfu(((const unsigned short*)&uv)[cf]);
            float h  = ((const float*)&hv)[cf];
            ((float*)&ov)[cf] = uu*h + (1.f - uu)*cc;
          }
          *(float4*)(cout + rowoff + o0) = ov;
        }
      }
    }
    // reset accumulators for the next row-tile (AFTER the full epilogue)
    #pragma unroll
    for (int rf=0; rf<2; rf++)
      #pragma unroll
      for (int cf=0; cf<CF; cf++) acc[rf][cf] = zero;
  }
}

// ---------------- launcher ----------------
extern "C" void kernel_launch(void* const* d_in, const int* in_sizes, int n_in,
                              void* d_out, int out_size, void* d_ws, size_t ws_size,
                              hipStream_t stream){
  const float* inputs = (const float*)d_in[0];
  const float* hx     = (const float*)d_in[1];
  const int*   row0   = (const int*)d_in[2];
  const int*   col0   = (const int*)d_in[3];
  const float* val0   = (const float*)d_in[4];
  const int*   row1   = (const int*)d_in[5];
  const int*   col1   = (const int*)d_in[6];
  const float* val1   = (const float*)d_in[7];
  const float* W_ru   = (const float*)d_in[8];
  const float* b_ru   = (const float*)d_in[9];
  const float* W_c    = (const float*)d_in[10];
  const float* b_c    = (const float*)d_in[11];
  float* out = (float*)d_out;

  char* ws = (char*)d_ws;
  size_t off = 0;
  auto alloc = [&](size_t bytes) -> void* {
    void* p = ws + off;
    off += (bytes + 255) & ~(size_t)255;
    return p;
  };
  unsigned short* xsS   = (unsigned short*)alloc((size_t)5*8*NN*256*2); // 163.84 MB
  unsigned int*   xsI   = (unsigned int*)  alloc((size_t)5*8*NN*16);    //   5.12 MB
  unsigned short* u_buf = (unsigned short*)alloc((size_t)NB*64*2);      //  32.77 MB
  unsigned short* Wru_t = (unsigned short*)alloc((size_t)128*352*2);
  unsigned short* Wc_t  = (unsigned short*)alloc((size_t)64*352*2);
  int*   row_ptr = (int*)  alloc(2*(NN+1)*4);
  int*   col_s   = (int*)  alloc(2*EE*4);
  float* val_s   = (float*)alloc(2*EE*4);
  int*   cnt     = (int*)  alloc(2*NN*4);
  int*   rp_work = (int*)  alloc(2*NN*4);
  (void)ws_size; (void)in_sizes; (void)n_in; (void)out_size;

  hipMemsetAsync(cnt, 0, 2*NN*4, stream);
  k_hist<<<(2*EE + 255)/256, 256, 0, stream>>>(row0, row1, cnt);
  k_scan<<<2, 1024, 0, stream>>>(cnt, row_ptr, rp_work);
  k_scatter<<<(2*EE + 255)/256, 256, 0, stream>>>(row0, col0, val0, row1, col1, val1, rp_work, col_s, val_s);
  k_wpack<<<(352*192)/256, 256, 0, stream>>>(W_ru, W_c, Wru_t, Wc_t);
  k_x0<<<NN, 256, 0, stream>>>(inputs, hx, (uint4*)xsS, (unsigned int*)xsI);

  uint4* xs4 = (uint4*)xsS;
  uint4* xi4 = (uint4*)xsI;

  // gconv 1: hop1 (both supports + input blocks), hop2 (both supports + input blocks)
  k_spmm<true ><<<16512, 256, 0, stream>>>(row_ptr, col_s, val_s, xs4, xi4, 0, 1, 0, 3);
  k_spmm<true ><<<16512, 256, 0, stream>>>(row_ptr, col_s, val_s, xs4, xi4, 1, 2, 3, 4);
  k_gemm<128, true><<<250, 256, 0, stream>>>(xsS, xsI, Wru_t, b_ru, hx, nullptr, u_buf);

  // gconv 2: state part = r*hx (in slab 0); input diffusion reused from gconv1
  k_spmm<false><<<16000, 256, 0, stream>>>(row_ptr, col_s, val_s, xs4, xi4, 0, 1, 0, 3);
  k_spmm<false><<<16000, 256, 0, stream>>>(row_ptr, col_s, val_s, xs4, xi4, 1, 2, 3, 4);
  k_gemm<64, false><<<250, 256, 0, stream>>>(xsS, xsI, Wc_t, b_c, hx, out, u_buf);
}

// Round 7
// 393.902 us; speedup vs baseline: 1.4662x; 1.0881x over previous
//
#include <hip/hip_runtime.h>
#include <stdint.h>

#define NN 8000            // nodes
#define UU 64              // units
#define EE 64000           // edges per support
#define BB 32              // batch
#define NB 256000          // NN*BB rows of the logical GEMM
#define HXS 512000         // NN*UU (per-batch stride in hx)

typedef __attribute__((ext_vector_type(8))) __bf16 bf16x8;
typedef __attribute__((ext_vector_type(4))) float f32x4;
typedef __attribute__((ext_vector_type(4))) unsigned int u32x4;

__device__ __forceinline__ unsigned short f2bf(float f){
  unsigned int u = __builtin_bit_cast(unsigned int, f);
  u += 0x7fffu + ((u >> 16) & 1u);
  return (unsigned short)(u >> 16);
}
__device__ __forceinline__ unsigned int pack2(float a, float b){
  return (unsigned int)f2bf(a) | ((unsigned int)f2bf(b) << 16);
}
__device__ __forceinline__ float bflo(unsigned int w){ return __builtin_bit_cast(float, w << 16); }
__device__ __forceinline__ float bfhi(unsigned int w){ return __builtin_bit_cast(float, w & 0xffff0000u); }
__device__ __forceinline__ float bfu(unsigned short v){ return __builtin_bit_cast(float, (unsigned int)v << 16); }

__device__ __forceinline__ void acc8(float* a, float v, uint4 q){
  a[0]+=v*bflo(q.x); a[1]+=v*bfhi(q.x); a[2]+=v*bflo(q.y); a[3]+=v*bfhi(q.y);
  a[4]+=v*bflo(q.z); a[5]+=v*bfhi(q.z); a[6]+=v*bflo(q.w); a[7]+=v*bfhi(q.w);
}

// async global->LDS, 16B per lane; LDS dest = wave-uniform base + lane*16 (linear).
__device__ __forceinline__ void stage16(const unsigned short* g, unsigned short* ldsbase){
  __builtin_amdgcn_global_load_lds((const __attribute__((address_space(1))) void*)g,
                                   (__attribute__((address_space(3))) void*)ldsbase, 16, 0, 0);
}

// ---------------- CSR build ----------------
__global__ void k_hist(const int* __restrict__ r0, const int* __restrict__ r1, int* __restrict__ cnt){
  int i = blockIdx.x * 256 + threadIdx.x;
  if (i < 2*EE){
    int s = (i >= EE);
    int r = s ? r1[i - EE] : r0[i];
    atomicAdd(&cnt[s*NN + r], 1);
  }
}

__global__ __launch_bounds__(1024) void k_scan(const int* __restrict__ cnt, int* __restrict__ row_ptr, int* __restrict__ rp_work){
  int sup = blockIdx.x;
  const int* c = cnt + sup*NN;
  __shared__ int part[1024];
  int t = threadIdx.x;
  int loc[8]; int s = 0;
  #pragma unroll
  for (int j=0;j<8;j++){ int idx=t*8+j; int v = (idx<NN)? c[idx]:0; loc[j]=s; s+=v; }
  part[t]=s; __syncthreads();
  for (int o=1;o<1024;o<<=1){
    int v = (t>=o)? part[t-o]:0;
    __syncthreads();
    part[t]+=v;
    __syncthreads();
  }
  int pre = (t>0)? part[t-1]:0;
  #pragma unroll
  for (int j=0;j<8;j++){ int idx=t*8+j; if(idx<NN){ int e=pre+loc[j]; row_ptr[sup*(NN+1)+idx]=e; rp_work[sup*NN+idx]=e; } }
  if (t==1023) row_ptr[sup*(NN+1)+NN] = part[1023];
}

__global__ void k_scatter(const int* __restrict__ r0, const int* __restrict__ c0, const float* __restrict__ v0,
                          const int* __restrict__ r1, const int* __restrict__ c1, const float* __restrict__ v1,
                          int* __restrict__ rp_work, int* __restrict__ col_s, float* __restrict__ val_s){
  int i = blockIdx.x * 256 + threadIdx.x;
  if (i < 2*EE){
    int s = (i >= EE);
    int e = s ? i - EE : i;
    int r  = s ? r1[e] : r0[e];
    int cc = s ? c1[e] : c0[e];
    float vv = s ? v1[e] : v0[e];
    int pos = atomicAdd(&rp_work[s*NN + r], 1);
    col_s[s*EE + pos] = cc;
    val_s[s*EE + pos] = vv;
  }
}

// ---------------- weight repack (Chebyshev absorbed, column-permuted) ----------------
// GEMM col c -> output unit o = 4*(c&15) + ((c>>4)&3); r/u block kept by c<64.
// Wp layout: m 0..4: [m][NCOL][64k] ; tail at 320*NCOL: [NCOL][32k]
__global__ void k_wpack(const float* __restrict__ W_ru, const float* __restrict__ W_c,
                        unsigned short* __restrict__ Wru_t, unsigned short* __restrict__ Wc_t){
  int i = blockIdx.x * 256 + threadIdx.x;   // 352*192 total
  int k = i / 192; int oo = i % 192;
  const float* W; int ld, NC; unsigned short* dst; int c;
  if (oo < 128){ W = W_ru; ld = 128; NC = 128; dst = Wru_t; c = oo; }
  else         { W = W_c;  ld = 64;  NC = 64;  dst = Wc_t;  c = oo - 128; }
  int o = 4*(c & 15) + ((c >> 4) & 3);
  int wcol = (c >= 64) ? 64 + o : o;
  float v = 0.f;
  if (k < 330){
    int m, fb;
    if (k < 320){ m = k >> 6; fb = (2 + (k & 63)) * 5; }
    else        { int j = k - 320; m = j >> 1; fb = (j & 1) * 5; }
    if      (m==0) v = W[(fb+0)*ld+wcol] - W[(fb+2)*ld+wcol] - W[(fb+4)*ld+wcol];
    else if (m==1) v = W[(fb+1)*ld+wcol];
    else if (m==2) v = 2.f*W[(fb+2)*ld+wcol];
    else if (m==3) v = W[(fb+3)*ld+wcol];
    else           v = 2.f*W[(fb+4)*ld+wcol];
  }
  int dstoff;
  if (k < 320) dstoff = (k>>6)*NC*64 + c*64 + (k&63);
  else         dstoff = 320*NC + c*32 + (k-320);
  dst[dstoff] = f2bf(v);
}

// ---------------- build x0 ----------------
// state slab per m: [16 slice][NN][2 bin][64 u] bf16 (slice = b>>1, bin = b&1)
// xi slab per m: [8 s][NN] uint4 (4 bins of dword)  -- unchanged layout
__global__ void k_x0(const float* __restrict__ inputs, const float* __restrict__ hx,
                     uint4* __restrict__ xs0q, unsigned int* __restrict__ xi0){
  int n = blockIdx.x, t = threadIdx.x;
  int b = t >> 3, ug = t & 7;
  const float4 h0 = *(const float4*)(hx + (size_t)b*HXS + n*64 + ug*8);
  const float4 h1 = *(const float4*)(hx + (size_t)b*HXS + n*64 + ug*8 + 4);
  uint4 o;
  o.x = pack2(h0.x, h0.y); o.y = pack2(h0.z, h0.w);
  o.z = pack2(h1.x, h1.y); o.w = pack2(h1.z, h1.w);
  xs0q[(size_t)(b>>1)*(NN*16) + (size_t)n*16 + (b&1)*8 + ug] = o;
  if (t < 32){
    int bb = t;
    const float2 g = *(const float2*)(inputs + (size_t)bb*(NN*2) + n*2);
    xi0[(((size_t)(bb>>2)*NN) + n)*4 + (bb&3)] = pack2(g.x, g.y);
  }
}

// ---------------- SpMM (16-sliced, XCD-sequenced; optional nt dst) ----------------
// state: 16000 blocks = 8 xcd x (2 sup x [500 grp slice=xcd | 500 grp slice=xcd+8])
// block = 16 subgroups x 16 lanes; subgroup owns one node row-slice (256B).
template<bool WITH_IN, bool NTDST>
__global__ void k_spmm(const int* __restrict__ row_ptr, const int* __restrict__ col_s, const float* __restrict__ val_s,
                       uint4* xs4, uint4* xi4,
                       int srcA, int dstA, int srcB, int dstB){
  int bid = blockIdx.x;
  if (WITH_IN && bid >= 16000){
    int b2 = bid - 16000;
    int s = b2 & 7, supi = (b2 >> 3) & 1, chunk = b2 >> 4;
    int n = chunk*256 + threadIdx.x;
    if (n >= NN) return;
    int msrc = supi ? srcB : srcA, mdst = supi ? dstB : dstA;
    size_t sb = (size_t)(msrc*8 + s)*NN, db = (size_t)(mdst*8 + s)*NN;
    int beg = row_ptr[supi*(NN+1)+n], end = row_ptr[supi*(NN+1)+n+1];
    const int* cs = col_s + supi*EE; const float* vs = val_s + supi*EE;
    float ai[8] = {0.f,0.f,0.f,0.f,0.f,0.f,0.f,0.f};
    for (int e = beg; e < end; ++e){
      int c = cs[e]; float v = vs[e];
      uint4 qi = xi4[sb + c];
      acc8(ai, v, qi);
    }
    uint4 oi;
    oi.x = pack2(ai[0],ai[1]); oi.y = pack2(ai[2],ai[3]); oi.z = pack2(ai[4],ai[5]); oi.w = pack2(ai[6],ai[7]);
    if (NTDST){
      u32x4 ov = {oi.x, oi.y, oi.z, oi.w};
      __builtin_nontemporal_store(ov, (u32x4*)&xi4[db + n]);
    } else xi4[db + n] = oi;
    return;
  }
  int xcd = bid & 7;
  int seq = bid >> 3;
  int supi = (seq >= 1000) ? 1 : 0;
  int seq2 = seq - supi*1000;
  int slice = (seq2 < 500) ? xcd : (xcd + 8);
  int group = (seq2 < 500) ? seq2 : (seq2 - 500);
  int sub = threadIdx.x >> 4, lane = threadIdx.x & 15;
  int n = group*16 + sub;
  int msrc = supi ? srcB : srcA, mdst = supi ? dstB : dstA;
  size_t sS = (size_t)msrc*(NN*256) + (size_t)slice*(NN*16);
  size_t dS = (size_t)mdst*(NN*256) + (size_t)slice*(NN*16);
  int beg = row_ptr[supi*(NN+1)+n], end = row_ptr[supi*(NN+1)+n+1];
  const int* cs = col_s + supi*EE;
  const float* vs = val_s + supi*EE;

  float a[8] = {0.f,0.f,0.f,0.f,0.f,0.f,0.f,0.f};
  int e = beg;
  for (; e + 4 <= end; e += 4){
    int c0=cs[e], c1=cs[e+1], c2=cs[e+2], c3=cs[e+3];
    float v0=vs[e], v1=vs[e+1], v2=vs[e+2], v3=vs[e+3];
    uint4 q0 = xs4[sS + (size_t)c0*16 + lane];
    uint4 q1 = xs4[sS + (size_t)c1*16 + lane];
    uint4 q2 = xs4[sS + (size_t)c2*16 + lane];
    uint4 q3 = xs4[sS + (size_t)c3*16 + lane];
    acc8(a, v0, q0); acc8(a, v1, q1); acc8(a, v2, q2); acc8(a, v3, q3);
  }
  for (; e < end; ++e){
    int c = cs[e]; float v = vs[e];
    uint4 q = xs4[sS + (size_t)c*16 + lane];
    acc8(a, v, q);
  }
  uint4 o;
  o.x = pack2(a[0],a[1]); o.y = pack2(a[2],a[3]); o.z = pack2(a[4],a[5]); o.w = pack2(a[6],a[7]);
  if (NTDST){
    u32x4 ov = {o.x, o.y, o.z, o.w};
    __builtin_nontemporal_store(ov, (u32x4*)&xs4[dS + (size_t)n*16 + lane]);
  } else xs4[dS + (size_t)n*16 + lane] = o;
}

// ---------------- GEMM: 4 independent 32-row waves, A global->reg dbuf, B via small LDS dbuf ----------------
template<int NCOL, bool IS_RU>
__global__ __launch_bounds__(256, 3) void k_gemm(unsigned short* xsS,                   // state slabs (slab0 = hx-bf16 / r*hx target)
                                                 const unsigned int* __restrict__ xsI,  // input dwords (8-slice layout)
                                                 const unsigned short* __restrict__ Wp, // packed [m][NCOL][64] + tail [NCOL][32]
                                                 const float* __restrict__ bias,
                                                 const float* __restrict__ hx,
                                                 float* cout,
                                                 unsigned short* ubuf){
  constexpr int CF = NCOL / 16;
  __shared__ unsigned short Bl[2][NCOL*64];
  __shared__ unsigned short Bt[NCOL*32];
  const int t = threadIdx.x;
  const int wv = t >> 6;
  const int l = t & 63;
  const int lr = l & 15;
  const int lg = l >> 4;
  const int R0 = blockIdx.x * 128;

  auto stageB = [&](int m, int buf){
    #pragma unroll
    for (int i=0;i<NCOL*8/256;i++){
      int g = t + i*256;
      int rr = g >> 3, c = g & 7;
      const unsigned short* gp = Wp + (size_t)(m*NCOL + rr)*64 + ((c ^ (rr&7)) << 3);
      stage16(gp, &Bl[buf][(size_t)(i*256 + wv*64)*8]);
    }
  };

  // per-wave A row bases (shorts)
  size_t abase[2];
  #pragma unroll
  for (int rf=0; rf<2; rf++){
    int row = R0 + wv*32 + rf*16 + lr;
    int n = row >> 5, b = row & 31;
    abase[rf] = (size_t)(b>>1)*(NN*128) + (size_t)n*128 + (b&1)*64;
  }
  auto loadA = [&](int m, uint4* dst){
    #pragma unroll
    for (int ks=0; ks<2; ks++)
      #pragma unroll
      for (int rf=0; rf<2; rf++)
        dst[ks*2+rf] = *(const uint4*)(xsS + (size_t)m*(NN*2048) + abase[rf] + ks*32 + lg*8);
  };

  // ---- prologue: A(m=0), tail frags, B0 + Btail ----
  uint4 aC[4], aN[4];
  loadA(0, aC);
  uint4 aT[2];
  #pragma unroll
  for (int rf=0; rf<2; rf++){
    int row = R0 + wv*32 + rf*16 + lr;
    int n = row >> 5, b = row & 31;
    size_t ib = (((size_t)(b>>2))*NN + n)*4 + (b&3);
    unsigned int q0=0u,q1=0u,q2=0u,q3=0u;
    if (lg == 0){
      q0 = xsI[ib];
      q1 = xsI[(size_t)8*NN*4 + ib];
      q2 = xsI[(size_t)16*NN*4 + ib];
      q3 = xsI[(size_t)24*NN*4 + ib];
    } else if (lg == 1){
      q0 = xsI[(size_t)32*NN*4 + ib];
    }
    uint4 qq; qq.x=q0; qq.y=q1; qq.z=q2; qq.w=q3;
    aT[rf] = qq;
  }
  stageB(0, 0);
  {
    #pragma unroll
    for (int i=0;i<NCOL*4/256;i++){
      int g = t + i*256;
      int rr = g >> 2, c = g & 3;
      const unsigned short* gp = Wp + (size_t)320*NCOL + rr*32 + ((c ^ (rr&3)) << 3);
      stage16(gp, &Bt[(size_t)(i*256 + wv*64)*8]);
    }
  }
  __syncthreads();

  f32x4 acc[2][CF];
  const f32x4 zero = {0.f,0.f,0.f,0.f};
  #pragma unroll
  for (int rf=0; rf<2; rf++)
    #pragma unroll
    for (int cf=0; cf<CF; cf++) acc[rf][cf] = zero;

  #pragma unroll
  for (int m=0; m<5; m++){
    int cur = m & 1;
    if (m < 4){
      stageB(m+1, cur^1);
      loadA(m+1, aN);
    }
    #pragma unroll
    for (int ks=0; ks<2; ks++){
      #pragma unroll
      for (int cf=0; cf<CF; cf++){
        int col = cf*16 + lr;
        int chunk = (ks*4 + lg) ^ (col & 7);
        bf16x8 bv = __builtin_bit_cast(bf16x8, *(const uint4*)(&Bl[cur][col*64 + chunk*8]));
        acc[0][cf] = __builtin_amdgcn_mfma_f32_16x16x32_bf16(__builtin_bit_cast(bf16x8, aC[ks*2+0]), bv, acc[0][cf], 0, 0, 0);
        acc[1][cf] = __builtin_amdgcn_mfma_f32_16x16x32_bf16(__builtin_bit_cast(bf16x8, aC[ks*2+1]), bv, acc[1][cf], 0, 0, 0);
      }
    }
    __syncthreads();
    #pragma unroll
    for (int i=0;i<4;i++) aC[i] = aN[i];
  }

  // ---- tail K-step (input features) ----
  #pragma unroll
  for (int cf=0; cf<CF; cf++){
    int col = cf*16 + lr;
    int chunk = lg ^ (col & 3);
    bf16x8 bv = __builtin_bit_cast(bf16x8, *(const uint4*)(&Bt[col*32 + chunk*8]));
    acc[0][cf] = __builtin_amdgcn_mfma_f32_16x16x32_bf16(__builtin_bit_cast(bf16x8, aT[0]), bv, acc[0][cf], 0, 0, 0);
    acc[1][cf] = __builtin_amdgcn_mfma_f32_16x16x32_bf16(__builtin_bit_cast(bf16x8, aT[1]), bv, acc[1][cf], 0, 0, 0);
  }

  // ---- epilogue (col c -> unit 4*lr+cf; vectorized stores) ----
  #pragma unroll
  for (int rf=0; rf<2; rf++){
    #pragma unroll
    for (int reg=0; reg<4; reg++){
      int row = R0 + wv*32 + rf*16 + (lg << 2) + reg;
      int n = row >> 5, b = row & 31;
      size_t rowoff = (size_t)b*HXS + (size_t)n*UU;
      size_t slot0 = (size_t)(b>>1)*(NN*128) + (size_t)n*128 + (b&1)*64;
      int o0 = lr << 2;
      if constexpr (IS_RU){
        uint2 hv = *(const uint2*)(xsS + slot0 + o0);   // hx bf16 (slab0, pre-overwrite)
        unsigned short rr4[4], uu4[4];
        #pragma unroll
        for (int cf=0; cf<4; cf++){
          int o = o0 + cf;
          float vr = acc[rf][cf][reg]   + bias[o];
          float vu = acc[rf][cf+4][reg] + bias[64+o];
          float sgr = 1.f/(1.f + __expf(-vr));
          float sgu = 1.f/(1.f + __expf(-vu));
          float h = bfu(((const unsigned short*)&hv)[cf]);
          rr4[cf] = f2bf(sgr * h);
          uu4[cf] = f2bf(sgu);
        }
        *(uint2*)(xsS + slot0 + o0) = *(uint2*)rr4;
        *(uint2*)(ubuf + rowoff + o0) = *(uint2*)uu4;
      } else {
        float4 hv = *(const float4*)(hx + rowoff + o0);
        uint2 uv = *(const uint2*)(ubuf + rowoff + o0);
        float4 ov;
        #pragma unroll
        for (int cf=0; cf<4; cf++){
          float cc = tanhf(acc[rf][cf][reg] + bias[o0+cf]);
          float uu = bfu(((const unsigned short*)&uv)[cf]);
          float h  = ((const float*)&hv)[cf];
          ((float*)&ov)[cf] = uu*h + (1.f - uu)*cc;
        }
        *(float4*)(cout + rowoff + o0) = ov;
      }
    }
  }
}

// ---------------- launcher ----------------
extern "C" void kernel_launch(void* const* d_in, const int* in_sizes, int n_in,
                              void* d_out, int out_size, void* d_ws, size_t ws_size,
                              hipStream_t stream){
  const float* inputs = (const float*)d_in[0];
  const float* hx     = (const float*)d_in[1];
  const int*   row0   = (const int*)d_in[2];
  const int*   col0   = (const int*)d_in[3];
  const float* val0   = (const float*)d_in[4];
  const int*   row1   = (const int*)d_in[5];
  const int*   col1   = (const int*)d_in[6];
  const float* val1   = (const float*)d_in[7];
  const float* W_ru   = (const float*)d_in[8];
  const float* b_ru   = (const float*)d_in[9];
  const float* W_c    = (const float*)d_in[10];
  const float* b_c    = (const float*)d_in[11];
  float* out = (float*)d_out;

  char* ws = (char*)d_ws;
  size_t off = 0;
  auto alloc = [&](size_t bytes) -> void* {
    void* p = ws + off;
    off += (bytes + 255) & ~(size_t)255;
    return p;
  };
  unsigned short* xsS   = (unsigned short*)alloc((size_t)5*NN*2048*2);  // 163.84 MB
  unsigned int*   xsI   = (unsigned int*)  alloc((size_t)5*8*NN*16);    //   5.12 MB
  unsigned short* u_buf = (unsigned short*)alloc((size_t)NB*64*2);      //  32.77 MB
  unsigned short* Wru_t = (unsigned short*)alloc((size_t)128*352*2);
  unsigned short* Wc_t  = (unsigned short*)alloc((size_t)64*352*2);
  int*   row_ptr = (int*)  alloc(2*(NN+1)*4);
  int*   col_s   = (int*)  alloc(2*EE*4);
  float* val_s   = (float*)alloc(2*EE*4);
  int*   cnt     = (int*)  alloc(2*NN*4);
  int*   rp_work = (int*)  alloc(2*NN*4);
  (void)ws_size; (void)in_sizes; (void)n_in; (void)out_size;

  hipMemsetAsync(cnt, 0, 2*NN*4, stream);
  k_hist<<<(2*EE + 255)/256, 256, 0, stream>>>(row0, row1, cnt);
  k_scan<<<2, 1024, 0, stream>>>(cnt, row_ptr, rp_work);
  k_scatter<<<(2*EE + 255)/256, 256, 0, stream>>>(row0, col0, val0, row1, col1, val1, rp_work, col_s, val_s);
  k_wpack<<<(352*192)/256, 256, 0, stream>>>(W_ru, W_c, Wru_t, Wc_t);
  k_x0<<<NN, 256, 0, stream>>>(inputs, hx, (uint4*)xsS, (unsigned int*)xsI);

  uint4* xs4 = (uint4*)xsS;
  uint4* xi4 = (uint4*)xsI;

  // gconv 1: hop1 (cached dst: slabs 1,3 are hop2 gather sources), hop2 (nt dst: slabs 2,4 only streamed by GEMM)
  k_spmm<true , false><<<16512, 256, 0, stream>>>(row_ptr, col_s, val_s, xs4, xi4, 0, 1, 0, 3);
  k_spmm<true , true ><<<16512, 256, 0, stream>>>(row_ptr, col_s, val_s, xs4, xi4, 1, 2, 3, 4);
  k_gemm<128, true><<<2000, 256, 0, stream>>>(xsS, xsI, Wru_t, b_ru, hx, nullptr, u_buf);

  // gconv 2: state part = r*hx (slab 0); input diffusion reused from gconv1
  k_spmm<false, false><<<16000, 256, 0, stream>>>(row_ptr, col_s, val_s, xs4, xi4, 0, 1, 0, 3);
  k_spmm<false, true ><<<16000, 256, 0, stream>>>(row_ptr, col_s, val_s, xs4, xi4, 1, 2, 3, 4);
  k_gemm<64, false><<<2000, 256, 0, stream>>>(xsS, xsI, Wc_t, b_c, hx, out, u_buf);
}